// Round 9
// baseline (609.211 us; speedup 1.0000x reference)
//
#include <hip/hip_runtime.h>

// ---------------------------------------------------------------------------
// BNN MC forward: 150 weight samples of a 784->512->512->512->10 MLP, batch 64.
// Reproduces jax.random (threefry2x32, partitionable=True) exactly (to well
// within the harness absmax threshold).
// R8: SPLIT weight-generation from GEMM (decisive experiment):
//   genw_kernel = pure streaming threefry+erfinv -> bf16 W in ws (no MFMA/LDS/
//   acc pressure, high occupancy); gemm_kernel = proven K-split layer minus
//   RNG. Guarded by ws_size; fallback = R7 fused path (proven, 454 us).
// ws (split-all): ~153 MB. (split-mid): ~104 MB. (fused): ~25 MB.
// ---------------------------------------------------------------------------

typedef short bf16x8 __attribute__((ext_vector_type(8)));
typedef int   i32x4  __attribute__((ext_vector_type(4)));
typedef float f32x4  __attribute__((ext_vector_type(4)));

#define TF_R(r) { x0 += x1; x1 = (x1 << (r)) | (x1 >> (32 - (r))); x1 ^= x0; }

// 8-chain round-major threefry pieces (a[8], b[8] in scope)
#define TF8(r) { _Pragma("unroll") for (int j = 0; j < 8; ++j) { \
    a[j] += b[j]; b[j] = (b[j] << (r)) | (b[j] >> (32 - (r))); b[j] ^= a[j]; } }
#define INJ8(kka, kkb) { _Pragma("unroll") for (int j = 0; j < 8; ++j) { \
    a[j] += (kka); b[j] += (kkb); } }

// Threefry-2x32, counter (0, c1), returns x0^x1 — scalar version (bias kernel)
__device__ __forceinline__ unsigned int tf_xor(unsigned int k0, unsigned int k1,
                                               unsigned int c1)
{
  const unsigned int ks2 = k0 ^ k1 ^ 0x1BD11BDAu;
  unsigned int x0 = k0;          // c0 = 0 (+ ks[0])
  unsigned int x1 = c1 + k1;
  TF_R(13) TF_R(15) TF_R(26) TF_R(6)
  x0 += k1;  x1 += ks2 + 1u;
  TF_R(17) TF_R(29) TF_R(16) TF_R(24)
  x0 += ks2; x1 += k0 + 2u;
  TF_R(13) TF_R(15) TF_R(26) TF_R(6)
  x0 += k0;  x1 += k1 + 3u;
  TF_R(17) TF_R(29) TF_R(16) TF_R(24)
  x0 += k1;  x1 += ks2 + 4u;
  TF_R(13) TF_R(15) TF_R(26) TF_R(6)
  x0 += ks2; x1 += k0 + 5u;
  return x0 ^ x1;
}

// bits -> g where eps = sqrt(2)*g; caller folds sqrt(2) into sigma.
// Branchless trimmed Giles erfinv (error << bf16 rounding, see R6 notes).
__device__ __forceinline__ float bits_to_g(unsigned int r)
{
  float f = __uint_as_float((r >> 9) | 0x3F800000u) - 1.0f;   // [0,1)
  float x = __builtin_fmaf(f, 2.0f, -0.99999994f);
  float L = __log2f(__builtin_fmaf(-x, x, 1.0f));             // log2(1-x^2) <= 0
  float t  = __builtin_fmaf(L, -0.6931472f, -2.5f);
  float pc = -4.39150654e-06f;
  pc = __builtin_fmaf(pc, t, 0.00021858087f);
  pc = __builtin_fmaf(pc, t, -0.00125372503f);
  pc = __builtin_fmaf(pc, t, -0.00417768164f);
  pc = __builtin_fmaf(pc, t, 0.246640727f);
  pc = __builtin_fmaf(pc, t, 1.50140941f);
  float w  = L * -0.6931472f;
  float t2 = sqrtf(w) - 3.0f;
  float pt = 0.00573950773f;
  pt = __builtin_fmaf(pt, t2, -0.0076224613f);
  pt = __builtin_fmaf(pt, t2, 0.00943887047f);
  pt = __builtin_fmaf(pt, t2, 1.00167406f);
  pt = __builtin_fmaf(pt, t2, 2.83297682f);
  float p = (L > -7.2134752f) ? pc : pt;    // w < 5
  return p * x;
}

__device__ __forceinline__ unsigned short f32_to_bf16_rne(float v)
{
  unsigned int u = __float_as_uint(v);
  unsigned int r = (u + 0x7FFFu + ((u >> 16) & 1u)) >> 16;   // RNE
  return (unsigned short)r;
}

// pack two f32 -> bf16x2 with RNE: round both in-register, one v_perm_b32.
__device__ __forceinline__ unsigned int pack_bf16_rne(float a, float b)
{
  unsigned int ua = __float_as_uint(a);
  unsigned int ub = __float_as_uint(b);
  ua += 0x7FFFu + ((ua >> 16) & 1u);
  ub += 0x7FFFu + ((ub >> 16) & 1u);
  return __builtin_amdgcn_perm(ub, ua, 0x07060302u);
}

// ---------------------------------------------------------------------------
// x (64,784) fp32 -> bf16, K padded 784 -> 832 with zeros
__global__ __launch_bounds__(256) void xpad_kernel(const float* __restrict__ x,
                                                   unsigned short* __restrict__ xp)
{
  int i = blockIdx.x * 256 + threadIdx.x;          // grid 208 -> 53248 == 64*832
  if (i >= 64 * 832) return;
  int m = i / 832, k = i - m * 832;
  float v = (k < 784) ? x[m * 784 + k] : 0.0f;
  xp[i] = f32_to_bf16_rne(v);
}

// ---------------------------------------------------------------------------
// Pack (mu, exp(v)*sqrt2) into [k/8][n][8] float2, zero-padded in k and n.
__global__ __launch_bounds__(256) void pack_kernel(
    const float* __restrict__ muW0, const float* __restrict__ vW0,
    const float* __restrict__ muW1, const float* __restrict__ vW1,
    const float* __restrict__ muW2, const float* __restrict__ vW2,
    const float* __restrict__ muW3, const float* __restrict__ vW3,
    float2* __restrict__ msP0, float2* __restrict__ msP1,
    float2* __restrict__ msP2, float2* __restrict__ msP3)
{
  int b = blockIdx.x, tid = threadIdx.x;
  const float* mu; const float* v; float2* o;
  int KV, NV, osh, base;
  if (b < 1664)      { mu = muW0; v = vW0; o = msP0; KV = 784; NV = 512; osh = 9; base = 0;    }
  else if (b < 2688) { mu = muW1; v = vW1; o = msP1; KV = 512; NV = 512; osh = 9; base = 1664; }
  else if (b < 3712) { mu = muW2; v = vW2; o = msP2; KV = 512; NV = 512; osh = 9; base = 2688; }
  else               { mu = muW3; v = vW3; o = msP3; KV = 512; NV = 10;  osh = 4; base = 3712; }
  int e = (b - base) * 256 + tid;
  int k = (e & 7) | ((e >> (3 + osh)) << 3);
  int n = (e >> 3) & ((1 << osh) - 1);
  float2 r = {0.0f, 0.0f};
  if (k < KV && n < NV) {
    r.x = mu[n * KV + k];
    r.y = __expf(v[n * KV + k]) * 1.41421356237f;
  }
  o[e] = r;
}

// ---------------------------------------------------------------------------
// Sample all 4 bias tensors -> fp32 in ws.  b_l[s][o] = mu[o] + exp(v[o])*eps
__global__ __launch_bounds__(256) void bias_kernel(
    const float* __restrict__ mu0, const float* __restrict__ v0, float* __restrict__ o0,
    const float* __restrict__ mu1, const float* __restrict__ v1, float* __restrict__ o1,
    const float* __restrict__ mu2, const float* __restrict__ v2, float* __restrict__ o2,
    const float* __restrict__ mu3, const float* __restrict__ v3, float* __restrict__ o3,
    unsigned int k00, unsigned int k01, unsigned int k10, unsigned int k11,
    unsigned int k20, unsigned int k21, unsigned int k30, unsigned int k31)
{
  int b = blockIdx.x, tid = threadIdx.x;
  int seg = b / 300; if (seg > 3) seg = 3;
  const float* mu; const float* v; float* o; unsigned int ka, kb; int n;
  if      (seg == 0) { mu = mu0; v = v0; o = o0; ka = k00; kb = k01; n = 76800; }
  else if (seg == 1) { mu = mu1; v = v1; o = o1; ka = k10; kb = k11; n = 76800; }
  else if (seg == 2) { mu = mu2; v = v2; o = o2; ka = k20; kb = k21; n = 76800; }
  else               { mu = mu3; v = v3; o = o3; ka = k30; kb = k31; n = 1500;  }
  int e = (b - seg * 300) * 256 + tid;
  if (e >= n) return;
  int oo = (seg == 3) ? (e % 10) : (e & 511);
  float eps = 1.41421356237f * bits_to_g(tf_xor(ka, kb, (unsigned int)e));
  o[e] = __builtin_fmaf(__expf(v[oo]), eps, mu[oo]);
}

// ---------------------------------------------------------------------------
// genw_kernel: pure weight generation. Thread -> (s, n, 32 consecutive k).
// W[s][n][k] bf16, row pitch KPAD; counters use KVALID stride (padded k have
// mu=sigma=0 in msP -> weight exactly 0). Pure VALU streaming: no MFMA, no
// LDS, no barriers -> high occupancy, clean scheduling.
template<int KVALID, int KPAD>
__global__ __launch_bounds__(256) void genw_kernel(
    unsigned short* __restrict__ W,        // [150][512][KPAD]
    const float2* __restrict__ msP,        // [KPAD/8][512][8] (mu, sigma*sqrt2)
    unsigned int k0, unsigned int k1)
{
  constexpr int CPR = KPAD / 32;           // 32-chunks per row (26 or 16)
  const unsigned int ks2 = k0 ^ k1 ^ 0x1BD11BDAu;
  const int e = blockIdx.x * 256 + threadIdx.x;   // [0, 512*CPR)
  const int s = blockIdx.y;
  const int n = e / CPR;
  const int c32 = e - n * CPR;
  const int k32 = c32 * 32;

  const unsigned int cb0 = (unsigned int)s * (unsigned int)(512 * KVALID)
                         + (unsigned int)n * (unsigned int)KVALID
                         + (unsigned int)k32;
  unsigned short* wp = W + ((size_t)(s * 512 + n) * KPAD + k32);

  #pragma unroll
  for (int h = 0; h < 4; ++h) {
    const int kb = k32 + h * 8;
    const float4* mp = reinterpret_cast<const float4*>(
        msP + ((size_t)(kb >> 3) * 512 + n) * 8);
    float4 q0 = mp[0], q1 = mp[1], q2 = mp[2], q3 = mp[3];

    unsigned int a[8], b[8];
    const unsigned int cb = cb0 + (unsigned int)(h * 8) + k1;
    #pragma unroll
    for (int j = 0; j < 8; ++j) { a[j] = k0; b[j] = cb + (unsigned int)j; }
    TF8(13) TF8(15) TF8(26) TF8(6)  INJ8(k1, ks2 + 1u)
    TF8(17) TF8(29) TF8(16) TF8(24) INJ8(ks2, k0 + 2u)
    TF8(13) TF8(15) TF8(26) TF8(6)  INJ8(k0, k1 + 3u)
    TF8(17) TF8(29) TF8(16) TF8(24) INJ8(k1, ks2 + 4u)
    TF8(13) TF8(15) TF8(26) TF8(6)  INJ8(ks2, k0 + 5u)

    float g[8];
    #pragma unroll
    for (int j = 0; j < 8; ++j)
      g[j] = bits_to_g(a[j] ^ b[j]);

    float wv[8];
    wv[0] = __builtin_fmaf(q0.y, g[0], q0.x);
    wv[1] = __builtin_fmaf(q0.w, g[1], q0.z);
    wv[2] = __builtin_fmaf(q1.y, g[2], q1.x);
    wv[3] = __builtin_fmaf(q1.w, g[3], q1.z);
    wv[4] = __builtin_fmaf(q2.y, g[4], q2.x);
    wv[5] = __builtin_fmaf(q2.w, g[5], q2.z);
    wv[6] = __builtin_fmaf(q3.y, g[6], q3.x);
    wv[7] = __builtin_fmaf(q3.w, g[7], q3.z);

    i32x4 bp;
    #pragma unroll
    for (int hh = 0; hh < 4; ++hh)
      bp[hh] = (int)pack_bf16_rne(wv[2 * hh], wv[2 * hh + 1]);
    *reinterpret_cast<i32x4*>(wp + h * 8) = bp;
  }
}

// ---------------------------------------------------------------------------
// gemm_kernel: K-split layer (same shape as fused) reading pre-generated W.
// block = 4 waves, one 16-col n-range x all 64 m x full K; LDS reduce;
// epilogue bias+relu, bf16 out (O=512 fixed).
template<int KPAD, int ASTRIDE, int AROW>
__global__ __launch_bounds__(256) void gemm_kernel(
    const unsigned short* __restrict__ A,   // bf16 [s][64][AROW]
    unsigned short* __restrict__ Out,       // bf16 [s][64][512]
    const unsigned short* __restrict__ W,   // bf16 [s][512][KPAD]
    const float* __restrict__ bS,           // [s][512]
    int unused0, int unused1)
{
  constexpr int NSTEPS = KPAD / 32;
  const int s    = blockIdx.y;
  const int tid  = threadIdx.x;
  const int wave = tid >> 6, lane = tid & 63;
  const int quad = lane >> 4;
  const int n16  = lane & 15;
  const int nlane = blockIdx.x * 16 + n16;

  const unsigned short* As = A + (size_t)s * ASTRIDE;
  const unsigned short* Wr = W + (size_t)(s * 512 + nlane) * KPAD;

  f32x4 acc[4] = {f32x4{0,0,0,0}, f32x4{0,0,0,0}, f32x4{0,0,0,0}, f32x4{0,0,0,0}};

  #pragma unroll 1
  for (int st = wave; st < NSTEPS; st += 4) {
    const int kb = st * 32 + quad * 8;
    bf16x8 afrag[4];
    #pragma unroll
    for (int mt = 0; mt < 4; ++mt)
      afrag[mt] = *reinterpret_cast<const bf16x8*>(
          As + (size_t)(mt * 16 + n16) * AROW + kb);
    bf16x8 bfrag = *reinterpret_cast<const bf16x8*>(Wr + kb);
    #pragma unroll
    for (int mt = 0; mt < 4; ++mt)
      acc[mt] = __builtin_amdgcn_mfma_f32_16x16x32_bf16(afrag[mt], bfrag, acc[mt], 0, 0, 0);
  }

  __shared__ float red[4 * 16 * 64];   // 16 KB
  #pragma unroll
  for (int mt = 0; mt < 4; ++mt)
    #pragma unroll
    for (int r = 0; r < 4; ++r)
      red[(wave * 16 + mt * 4 + r) * 64 + lane] = acc[mt][r];
  __syncthreads();

  const int m   = tid >> 2;
  const int nq  = (tid & 3) * 4;
  const int row = (m >> 4) * 4 + (m & 3);
  const int col = ((m >> 2) & 3) * 16 + nq;

  float4 p0 = *reinterpret_cast<const float4*>(&red[(0 * 16 + row) * 64 + col]);
  float4 p1 = *reinterpret_cast<const float4*>(&red[(1 * 16 + row) * 64 + col]);
  float4 p2 = *reinterpret_cast<const float4*>(&red[(2 * 16 + row) * 64 + col]);
  float4 p3 = *reinterpret_cast<const float4*>(&red[(3 * 16 + row) * 64 + col]);
  float v0 = (p0.x + p1.x) + (p2.x + p3.x);
  float v1 = (p0.y + p1.y) + (p2.y + p3.y);
  float v2 = (p0.z + p1.z) + (p2.z + p3.z);
  float v3 = (p0.w + p1.w) + (p2.w + p3.w);

  const float4 b4 = *reinterpret_cast<const float4*>(
      &bS[s * 512 + blockIdx.x * 16 + nq]);
  float o0 = fmaxf(v0 + b4.x, 0.0f), o1 = fmaxf(v1 + b4.y, 0.0f);
  float o2 = fmaxf(v2 + b4.z, 0.0f), o3 = fmaxf(v3 + b4.w, 0.0f);
  uint2 stv;
  stv.x = pack_bf16_rne(o0, o1);
  stv.y = pack_bf16_rne(o2, o3);
  *reinterpret_cast<uint2*>(
      Out + ((size_t)s * 64 + m) * 512 + blockIdx.x * 16 + nq) = stv;
}

// ---------------------------------------------------------------------------
// R7 fused layer (fallback + L3). See R7 notes.
template<int KVALID, int KPAD, int OVALID, int OPITCH, int ASTRIDE, int AROW,
         bool RELU, bool F32OUT>
__global__
__attribute__((amdgpu_flat_work_group_size(256, 256)))
__attribute__((amdgpu_waves_per_eu(1, 4)))
void layer_fused(
    const unsigned short* __restrict__ A,
    void* __restrict__ OutV,
    const float2* __restrict__ msP,
    const float* __restrict__ bS,
    unsigned int k0, unsigned int k1)
{
  constexpr int NSTEPS = KPAD / 32;
  const unsigned int ks2 = k0 ^ k1 ^ 0x1BD11BDAu;
  const int s    = blockIdx.y;
  const int tid  = threadIdx.x;
  const int wave = tid >> 6, lane = tid & 63;
  const int quad = lane >> 4;
  const int n16  = lane & 15;
  const int nlane = blockIdx.x * 16 + n16;

  const unsigned short* As = A + (size_t)s * ASTRIDE;
  const unsigned int idx_base = (unsigned int)s * (unsigned int)(OVALID * KVALID)
                              + (unsigned int)nlane * (unsigned int)KVALID;

  f32x4 acc[4] = {f32x4{0,0,0,0}, f32x4{0,0,0,0}, f32x4{0,0,0,0}, f32x4{0,0,0,0}};

  auto load_step = [&](int st, bf16x8 (&af)[4], float4 (&q)[4]) {
    const int kb = st * 32 + quad * 8;
    #pragma unroll
    for (int mt = 0; mt < 4; ++mt)
      af[mt] = *reinterpret_cast<const bf16x8*>(
          As + (size_t)(mt * 16 + n16) * AROW + kb);
    const float4* mp = reinterpret_cast<const float4*>(
        msP + ((size_t)(kb >> 3) * OPITCH + nlane) * 8);
    #pragma unroll
    for (int h = 0; h < 4; ++h)
      q[h] = mp[h];
  };

  auto compute_step = [&](int st, bf16x8 (&af)[4], float4 (&q)[4]) {
    const int kb = st * 32 + quad * 8;
    unsigned int a[8], b[8];
    const unsigned int cb = idx_base + (unsigned int)kb + k1;
    #pragma unroll
    for (int j = 0; j < 8; ++j) { a[j] = k0; b[j] = cb + (unsigned int)j; }
    TF8(13) TF8(15) TF8(26) TF8(6)  INJ8(k1, ks2 + 1u)
    TF8(17) TF8(29) TF8(16) TF8(24) INJ8(ks2, k0 + 2u)
    TF8(13) TF8(15) TF8(26) TF8(6)  INJ8(k0, k1 + 3u)
    TF8(17) TF8(29) TF8(16) TF8(24) INJ8(k1, ks2 + 4u)
    TF8(13) TF8(15) TF8(26) TF8(6)  INJ8(ks2, k0 + 5u)

    float g[8];
    #pragma unroll
    for (int j = 0; j < 8; ++j)
      g[j] = bits_to_g(a[j] ^ b[j]);

    float wv[8];
    wv[0] = __builtin_fmaf(q[0].y, g[0], q[0].x);
    wv[1] = __builtin_fmaf(q[0].w, g[1], q[0].z);
    wv[2] = __builtin_fmaf(q[1].y, g[2], q[1].x);
    wv[3] = __builtin_fmaf(q[1].w, g[3], q[1].z);
    wv[4] = __builtin_fmaf(q[2].y, g[4], q[2].x);
    wv[5] = __builtin_fmaf(q[2].w, g[5], q[2].z);
    wv[6] = __builtin_fmaf(q[3].y, g[6], q[3].x);
    wv[7] = __builtin_fmaf(q[3].w, g[7], q[3].z);

    i32x4 bp;
    #pragma unroll
    for (int h = 0; h < 4; ++h)
      bp[h] = (int)pack_bf16_rne(wv[2 * h], wv[2 * h + 1]);
    bf16x8 bfrag = __builtin_bit_cast(bf16x8, bp);

    #pragma unroll
    for (int mt = 0; mt < 4; ++mt)
      acc[mt] = __builtin_amdgcn_mfma_f32_16x16x32_bf16(af[mt], bfrag, acc[mt], 0, 0, 0);
  };

  bf16x8 afA[4], afB[4];
  float4 qA[4], qB[4];
  int st = wave;
  if (st < NSTEPS) load_step(st, afA, qA);
  while (st < NSTEPS) {
    int n1 = st + 4;
    if (n1 < NSTEPS) load_step(n1, afB, qB);
    __builtin_amdgcn_sched_barrier(0);
    compute_step(st, afA, qA);
    st = n1;
    if (st >= NSTEPS) break;
    int n2 = st + 4;
    if (n2 < NSTEPS) load_step(n2, afA, qA);
    __builtin_amdgcn_sched_barrier(0);
    compute_step(st, afB, qB);
    st = n2;
  }

  __shared__ float red[4 * 16 * 64];
  #pragma unroll
  for (int mt = 0; mt < 4; ++mt)
    #pragma unroll
    for (int r = 0; r < 4; ++r)
      red[(wave * 16 + mt * 4 + r) * 64 + lane] = acc[mt][r];
  __syncthreads();

  const int m   = tid >> 2;
  const int nq  = (tid & 3) * 4;
  const int row = (m >> 4) * 4 + (m & 3);
  const int col = ((m >> 2) & 3) * 16 + nq;

  float4 p0 = *reinterpret_cast<const float4*>(&red[(0 * 16 + row) * 64 + col]);
  float4 p1 = *reinterpret_cast<const float4*>(&red[(1 * 16 + row) * 64 + col]);
  float4 p2 = *reinterpret_cast<const float4*>(&red[(2 * 16 + row) * 64 + col]);
  float4 p3 = *reinterpret_cast<const float4*>(&red[(3 * 16 + row) * 64 + col]);
  float v0 = (p0.x + p1.x) + (p2.x + p3.x);
  float v1 = (p0.y + p1.y) + (p2.y + p3.y);
  float v2 = (p0.z + p1.z) + (p2.z + p3.z);
  float v3 = (p0.w + p1.w) + (p2.w + p3.w);

  if (F32OUT) {
    float* Out = (float*)OutV;
    float vv[4] = {v0, v1, v2, v3};
    #pragma unroll
    for (int jj = 0; jj < 4; ++jj) {
      int nn = nq + jj;
      if (nn < OVALID)
        Out[((size_t)s * 64 + m) * OVALID + nn] = vv[jj] + bS[s * OVALID + nn];
    }
  } else {
    const float4 b4 = *reinterpret_cast<const float4*>(
        &bS[s * OVALID + blockIdx.x * 16 + nq]);
    float o0 = v0 + b4.x, o1 = v1 + b4.y, o2 = v2 + b4.z, o3 = v3 + b4.w;
    if (RELU) {
      o0 = fmaxf(o0, 0.0f); o1 = fmaxf(o1, 0.0f);
      o2 = fmaxf(o2, 0.0f); o3 = fmaxf(o3, 0.0f);
    }
    uint2 stv;
    stv.x = pack_bf16_rne(o0, o1);
    stv.y = pack_bf16_rne(o2, o3);
    *reinterpret_cast<uint2*>(
        (unsigned short*)OutV + ((size_t)s * 64 + m) * OPITCH + blockIdx.x * 16 + nq) = stv;
  }
}

// ---------------------------------------------------------------------------
// Host-side threefry for jax.random.split(key(1), 8)
static void tf_host(unsigned int k0, unsigned int k1, unsigned int c0, unsigned int c1,
                    unsigned int* o0, unsigned int* o1)
{
  const unsigned int ks2 = k0 ^ k1 ^ 0x1BD11BDAu;
  unsigned int x0 = c0 + k0, x1 = c1 + k1;
  TF_R(13) TF_R(15) TF_R(26) TF_R(6)
  x0 += k1;  x1 += ks2 + 1u;
  TF_R(17) TF_R(29) TF_R(16) TF_R(24)
  x0 += ks2; x1 += k0 + 2u;
  TF_R(13) TF_R(15) TF_R(26) TF_R(6)
  x0 += k0;  x1 += k1 + 3u;
  TF_R(17) TF_R(29) TF_R(16) TF_R(24)
  x0 += k1;  x1 += ks2 + 4u;
  TF_R(13) TF_R(15) TF_R(26) TF_R(6)
  x0 += ks2; x1 += k0 + 5u;
  *o0 = x0; *o1 = x1;
}

extern "C" void kernel_launch(void* const* d_in, const int* in_sizes, int n_in,
                              void* d_out, int out_size, void* d_ws, size_t ws_size,
                              hipStream_t stream)
{
  (void)in_sizes; (void)n_in; (void)out_size;

  const float* x    = (const float*)d_in[0];
  const float* muW0 = (const float*)d_in[1];
  const float* mub0 = (const float*)d_in[2];
  const float* muW1 = (const float*)d_in[3];
  const float* mub1 = (const float*)d_in[4];
  const float* muW2 = (const float*)d_in[5];
  const float* mub2 = (const float*)d_in[6];
  const float* muW3 = (const float*)d_in[7];
  const float* mub3 = (const float*)d_in[8];
  const float* vW0  = (const float*)d_in[9];
  const float* vb0  = (const float*)d_in[10];
  const float* vW1  = (const float*)d_in[11];
  const float* vb1  = (const float*)d_in[12];
  const float* vW2  = (const float*)d_in[13];
  const float* vb2  = (const float*)d_in[14];
  const float* vW3  = (const float*)d_in[15];
  const float* vb3  = (const float*)d_in[16];

  unsigned int key[8][2];
  for (unsigned int i = 0; i < 8; ++i)
    tf_host(0u, 1u, 0u, i, &key[i][0], &key[i][1]);

  // ws layout (fused core ~25 MB; W buffer appended for split paths)
  char* ws = (char*)d_ws;
  unsigned short* xp = (unsigned short*)(ws);                 // 106,496
  unsigned short* hA = (unsigned short*)(ws + 106496);        // 9,830,400
  float* b0s  = (float*)(ws + 9936896);
  float* b1s  = (float*)(ws + 10244096);
  float* b2s  = (float*)(ws + 10551296);
  float* b3s  = (float*)(ws + 10858496);
  float2* msP1 = (float2*)(ws + 10866688);                    // 2,097,152
  float2* msP2 = (float2*)(ws + 12963840);                    // 2,097,152
  float2* msP3 = (float2*)(ws + 15060992);                    // 65,536
  float2* msP0 = (float2*)(ws + 15126528);                    // 3,407,872
  unsigned short* hB = (unsigned short*)(ws + 15126528);      // aliases msP0
  unsigned short* Wbuf = (unsigned short*)(ws + 25165824);    // up to 127,795,200

  const bool splitMid = ws_size >= (size_t)25165824 + 78643200u;   // ~104 MB
  const bool splitL0  = ws_size >= (size_t)25165824 + 127795200u;  // ~153 MB

  xpad_kernel<<<208, 256, 0, stream>>>(x, xp);
  pack_kernel<<<3744, 256, 0, stream>>>(muW0, vW0, muW1, vW1, muW2, vW2, muW3, vW3,
                                        msP0, msP1, msP2, msP3);
  bias_kernel<<<906, 256, 0, stream>>>(mub0, vb0, b0s, mub1, vb1, b1s,
                                       mub2, vb2, b2s, mub3, vb3, b3s,
                                       key[1][0], key[1][1], key[3][0], key[3][1],
                                       key[5][0], key[5][1], key[7][0], key[7][1]);

  // L0: x(64,784 pad 832) -> hA
  if (splitL0) {
    genw_kernel<784, 832><<<dim3(52, 150), 256, 0, stream>>>(
        Wbuf, msP0, key[0][0], key[0][1]);
    gemm_kernel<832, 0, 832><<<dim3(32, 150), 256, 0, stream>>>(
        xp, hA, Wbuf, b0s, 0, 0);
  } else {
    layer_fused<784, 832, 512, 512, 0, 832, true, false>
        <<<dim3(32, 150), 256, 0, stream>>>(xp, hA, msP0, b0s, key[0][0], key[0][1]);
  }

  // L1: hA -> hB (kills msP0) ; L2: hB -> hA
  if (splitMid) {
    genw_kernel<512, 512><<<dim3(32, 150), 256, 0, stream>>>(
        Wbuf, msP1, key[2][0], key[2][1]);
    gemm_kernel<512, 32768, 512><<<dim3(32, 150), 256, 0, stream>>>(
        hA, hB, Wbuf, b1s, 0, 0);
    genw_kernel<512, 512><<<dim3(32, 150), 256, 0, stream>>>(
        Wbuf, msP2, key[4][0], key[4][1]);
    gemm_kernel<512, 32768, 512><<<dim3(32, 150), 256, 0, stream>>>(
        hB, hA, Wbuf, b2s, 0, 0);
  } else {
    layer_fused<512, 512, 512, 512, 32768, 512, true, false>
        <<<dim3(32, 150), 256, 0, stream>>>(hA, hB, msP1, b1s, key[2][0], key[2][1]);
    layer_fused<512, 512, 512, 512, 32768, 512, true, false>
        <<<dim3(32, 150), 256, 0, stream>>>(hB, hA, msP2, b2s, key[4][0], key[4][1]);
  }

  // L3: hA -> out (tiny, stays fused)
  layer_fused<512, 512, 10, 16, 32768, 512, false, true>
      <<<dim3(1, 150), 256, 0, stream>>>(hA, d_out, msP3, b3s, key[6][0], key[6][1]);
}

// Round 10
// 455.936 us; speedup vs baseline: 1.3362x; 1.3362x over previous
//
#include <hip/hip_runtime.h>

// ---------------------------------------------------------------------------
// BNN MC forward: 150 weight samples of a 784->512->512->512->10 MLP, batch 64.
// Reproduces jax.random (threefry2x32, partitionable=True) exactly (to well
// within the harness absmax threshold).
// R9 = R7 (best: 454 us) + XCD-affinity swizzle: all 32 n-blocks of sample s
// land on XCD s&7 (1D grid, bid = ((s>>3)*32+x)*8 + (s&7)) -> hA[s] read 32x
// from local L2 instead of L3, and layer L's writes land where layer L+1
// reads. Evidence: L0 (shared 106KB x, L1-hot) runs 1.6x faster per k-step
// than mids (9.8MB hA > 4MB per-XCD L2). R8 split proved RNG stream + GEMM
// fusion is nearly free; occupancy/reg theories exonerated.
// ws usage ~25.0 MB (hB aliases msP0).
// ---------------------------------------------------------------------------

typedef short bf16x8 __attribute__((ext_vector_type(8)));
typedef int   i32x4  __attribute__((ext_vector_type(4)));
typedef float f32x4  __attribute__((ext_vector_type(4)));

#define TF_R(r) { x0 += x1; x1 = (x1 << (r)) | (x1 >> (32 - (r))); x1 ^= x0; }

// 8-chain round-major threefry pieces (a[8], b[8] in scope)
#define TF8(r) { _Pragma("unroll") for (int j = 0; j < 8; ++j) { \
    a[j] += b[j]; b[j] = (b[j] << (r)) | (b[j] >> (32 - (r))); b[j] ^= a[j]; } }
#define INJ8(kka, kkb) { _Pragma("unroll") for (int j = 0; j < 8; ++j) { \
    a[j] += (kka); b[j] += (kkb); } }

// Threefry-2x32, counter (0, c1), returns x0^x1 — scalar version (bias kernel)
__device__ __forceinline__ unsigned int tf_xor(unsigned int k0, unsigned int k1,
                                               unsigned int c1)
{
  const unsigned int ks2 = k0 ^ k1 ^ 0x1BD11BDAu;
  unsigned int x0 = k0;          // c0 = 0 (+ ks[0])
  unsigned int x1 = c1 + k1;
  TF_R(13) TF_R(15) TF_R(26) TF_R(6)
  x0 += k1;  x1 += ks2 + 1u;
  TF_R(17) TF_R(29) TF_R(16) TF_R(24)
  x0 += ks2; x1 += k0 + 2u;
  TF_R(13) TF_R(15) TF_R(26) TF_R(6)
  x0 += k0;  x1 += k1 + 3u;
  TF_R(17) TF_R(29) TF_R(16) TF_R(24)
  x0 += k1;  x1 += ks2 + 4u;
  TF_R(13) TF_R(15) TF_R(26) TF_R(6)
  x0 += ks2; x1 += k0 + 5u;
  return x0 ^ x1;
}

// bits -> g where eps = sqrt(2)*g; caller folds sqrt(2) into sigma.
// Branchless trimmed Giles erfinv (error << bf16 rounding, see R6 notes).
__device__ __forceinline__ float bits_to_g(unsigned int r)
{
  float f = __uint_as_float((r >> 9) | 0x3F800000u) - 1.0f;   // [0,1)
  float x = __builtin_fmaf(f, 2.0f, -0.99999994f);
  float L = __log2f(__builtin_fmaf(-x, x, 1.0f));             // log2(1-x^2) <= 0
  float t  = __builtin_fmaf(L, -0.6931472f, -2.5f);
  float pc = -4.39150654e-06f;
  pc = __builtin_fmaf(pc, t, 0.00021858087f);
  pc = __builtin_fmaf(pc, t, -0.00125372503f);
  pc = __builtin_fmaf(pc, t, -0.00417768164f);
  pc = __builtin_fmaf(pc, t, 0.246640727f);
  pc = __builtin_fmaf(pc, t, 1.50140941f);
  float w  = L * -0.6931472f;
  float t2 = sqrtf(w) - 3.0f;
  float pt = 0.00573950773f;
  pt = __builtin_fmaf(pt, t2, -0.0076224613f);
  pt = __builtin_fmaf(pt, t2, 0.00943887047f);
  pt = __builtin_fmaf(pt, t2, 1.00167406f);
  pt = __builtin_fmaf(pt, t2, 2.83297682f);
  float p = (L > -7.2134752f) ? pc : pt;    // w < 5
  return p * x;
}

__device__ __forceinline__ unsigned short f32_to_bf16_rne(float v)
{
  unsigned int u = __float_as_uint(v);
  unsigned int r = (u + 0x7FFFu + ((u >> 16) & 1u)) >> 16;   // RNE
  return (unsigned short)r;
}

// pack two f32 -> bf16x2 with RNE: round both in-register, one v_perm_b32.
__device__ __forceinline__ unsigned int pack_bf16_rne(float a, float b)
{
  unsigned int ua = __float_as_uint(a);
  unsigned int ub = __float_as_uint(b);
  ua += 0x7FFFu + ((ua >> 16) & 1u);
  ub += 0x7FFFu + ((ub >> 16) & 1u);
  return __builtin_amdgcn_perm(ub, ua, 0x07060302u);
}

// ---------------------------------------------------------------------------
// x (64,784) fp32 -> bf16, K padded 784 -> 832 with zeros
__global__ __launch_bounds__(256) void xpad_kernel(const float* __restrict__ x,
                                                   unsigned short* __restrict__ xp)
{
  int i = blockIdx.x * 256 + threadIdx.x;          // grid 208 -> 53248 == 64*832
  if (i >= 64 * 832) return;
  int m = i / 832, k = i - m * 832;
  float v = (k < 784) ? x[m * 784 + k] : 0.0f;
  xp[i] = f32_to_bf16_rne(v);
}

// ---------------------------------------------------------------------------
// Pack (mu, exp(v)*sqrt2) into [k/8][n][8] float2, zero-padded in k and n.
__global__ __launch_bounds__(256) void pack_kernel(
    const float* __restrict__ muW0, const float* __restrict__ vW0,
    const float* __restrict__ muW1, const float* __restrict__ vW1,
    const float* __restrict__ muW2, const float* __restrict__ vW2,
    const float* __restrict__ muW3, const float* __restrict__ vW3,
    float2* __restrict__ msP0, float2* __restrict__ msP1,
    float2* __restrict__ msP2, float2* __restrict__ msP3)
{
  int b = blockIdx.x, tid = threadIdx.x;
  const float* mu; const float* v; float2* o;
  int KV, NV, osh, base;
  if (b < 1664)      { mu = muW0; v = vW0; o = msP0; KV = 784; NV = 512; osh = 9; base = 0;    }
  else if (b < 2688) { mu = muW1; v = vW1; o = msP1; KV = 512; NV = 512; osh = 9; base = 1664; }
  else if (b < 3712) { mu = muW2; v = vW2; o = msP2; KV = 512; NV = 512; osh = 9; base = 2688; }
  else               { mu = muW3; v = vW3; o = msP3; KV = 512; NV = 10;  osh = 4; base = 3712; }
  int e = (b - base) * 256 + tid;
  int k = (e & 7) | ((e >> (3 + osh)) << 3);
  int n = (e >> 3) & ((1 << osh) - 1);
  float2 r = {0.0f, 0.0f};
  if (k < KV && n < NV) {
    r.x = mu[n * KV + k];
    r.y = __expf(v[n * KV + k]) * 1.41421356237f;
  }
  o[e] = r;
}

// ---------------------------------------------------------------------------
// Sample all 4 bias tensors -> fp32 in ws.  b_l[s][o] = mu[o] + exp(v[o])*eps
__global__ __launch_bounds__(256) void bias_kernel(
    const float* __restrict__ mu0, const float* __restrict__ v0, float* __restrict__ o0,
    const float* __restrict__ mu1, const float* __restrict__ v1, float* __restrict__ o1,
    const float* __restrict__ mu2, const float* __restrict__ v2, float* __restrict__ o2,
    const float* __restrict__ mu3, const float* __restrict__ v3, float* __restrict__ o3,
    unsigned int k00, unsigned int k01, unsigned int k10, unsigned int k11,
    unsigned int k20, unsigned int k21, unsigned int k30, unsigned int k31)
{
  int b = blockIdx.x, tid = threadIdx.x;
  int seg = b / 300; if (seg > 3) seg = 3;
  const float* mu; const float* v; float* o; unsigned int ka, kb; int n;
  if      (seg == 0) { mu = mu0; v = v0; o = o0; ka = k00; kb = k01; n = 76800; }
  else if (seg == 1) { mu = mu1; v = v1; o = o1; ka = k10; kb = k11; n = 76800; }
  else if (seg == 2) { mu = mu2; v = v2; o = o2; ka = k20; kb = k21; n = 76800; }
  else               { mu = mu3; v = v3; o = o3; ka = k30; kb = k31; n = 1500;  }
  int e = (b - seg * 300) * 256 + tid;
  if (e >= n) return;
  int oo = (seg == 3) ? (e % 10) : (e & 511);
  float eps = 1.41421356237f * bits_to_g(tf_xor(ka, kb, (unsigned int)e));
  o[e] = __builtin_fmaf(__expf(v[oo]), eps, mu[oo]);
}

// ---------------------------------------------------------------------------
// Fused layer (R7 structure) + XCD-affinity swizzle for the big layers:
//   1D grid 4864; bid = ((s>>3)*32 + x)*8 + (s&7) -> XCD = s&7 under
//   round-robin dispatch; blocks with s >= 150 return immediately (uniform).
//   block = 4 waves, one 16-col n-range x all 64 m x full K; K-split across
//   waves; ping-pong register prefetch pinned with sched_barrier(0);
//   LDS reduce; epilogue bias(+relu).
// amdgpu_waves_per_eu(1,4): scheduler targets 4 waves/EU, freeing <=128 VGPR.
// mfma_f32_16x16x32_bf16: A/B frag lane holds row (lane&15), k=(lane>>4)*8+j;
// C/D lane holds col n=(lane&15), rows m=(lane>>4)*4+reg.
template<int KVALID, int KPAD, int OVALID, int OPITCH, int ASTRIDE, int AROW,
         bool RELU, bool F32OUT>
__global__
__attribute__((amdgpu_flat_work_group_size(256, 256)))
__attribute__((amdgpu_waves_per_eu(1, 4)))
void layer_fused(
    const unsigned short* __restrict__ A,   // bf16 [s][64][AROW] (ASTRIDE=0: shared x)
    void* __restrict__ OutV,                // bf16 [s][64][OPITCH] or f32 [s][64][OVALID]
    const float2* __restrict__ msP,         // [KPAD/8][OPITCH][8] (mu, sigma*sqrt2)
    const float* __restrict__ bS,           // [s][OVALID]
    unsigned int k0, unsigned int k1)
{
  constexpr int NSTEPS = KPAD / 32;
  constexpr bool SW = (OPITCH == 512);      // big layers: swizzled 1D grid
  const unsigned int ks2 = k0 ^ k1 ^ 0x1BD11BDAu;

  int s, bx;
  if constexpr (SW) {
    const int low3 = blockIdx.x & 7;
    const int q    = blockIdx.x >> 3;
    bx = q & 31;                             // n-block 0..31
    s  = ((q >> 5) << 3) | low3;             // sample
    if (s >= 150) return;                    // uniform early-out (pre-barrier)
  } else {
    s = blockIdx.y; bx = blockIdx.x;
  }

  const int tid  = threadIdx.x;
  const int wave = tid >> 6, lane = tid & 63;
  const int quad = lane >> 4;
  const int n16  = lane & 15;
  const int nlane = bx * 16 + n16;

  const unsigned short* As = A + (size_t)s * ASTRIDE;
  const unsigned int idx_base = (unsigned int)s * (unsigned int)(OVALID * KVALID)
                              + (unsigned int)nlane * (unsigned int)KVALID;

  f32x4 acc[4] = {f32x4{0,0,0,0}, f32x4{0,0,0,0}, f32x4{0,0,0,0}, f32x4{0,0,0,0}};

  auto load_step = [&](int st, bf16x8 (&af)[4], float4 (&q)[4]) {
    const int kb = st * 32 + quad * 8;
    #pragma unroll
    for (int mt = 0; mt < 4; ++mt)
      af[mt] = *reinterpret_cast<const bf16x8*>(
          As + (size_t)(mt * 16 + n16) * AROW + kb);
    const float4* mp = reinterpret_cast<const float4*>(
        msP + ((size_t)(kb >> 3) * OPITCH + nlane) * 8);
    #pragma unroll
    for (int h = 0; h < 4; ++h)
      q[h] = mp[h];
  };

  auto compute_step = [&](int st, bf16x8 (&af)[4], float4 (&q)[4]) {
    const int kb = st * 32 + quad * 8;
    unsigned int a[8], b[8];
    const unsigned int cb = idx_base + (unsigned int)kb + k1;
    #pragma unroll
    for (int j = 0; j < 8; ++j) { a[j] = k0; b[j] = cb + (unsigned int)j; }
    TF8(13) TF8(15) TF8(26) TF8(6)  INJ8(k1, ks2 + 1u)
    TF8(17) TF8(29) TF8(16) TF8(24) INJ8(ks2, k0 + 2u)
    TF8(13) TF8(15) TF8(26) TF8(6)  INJ8(k0, k1 + 3u)
    TF8(17) TF8(29) TF8(16) TF8(24) INJ8(k1, ks2 + 4u)
    TF8(13) TF8(15) TF8(26) TF8(6)  INJ8(ks2, k0 + 5u)

    float g[8];
    #pragma unroll
    for (int j = 0; j < 8; ++j)
      g[j] = bits_to_g(a[j] ^ b[j]);

    float wv[8];
    wv[0] = __builtin_fmaf(q[0].y, g[0], q[0].x);
    wv[1] = __builtin_fmaf(q[0].w, g[1], q[0].z);
    wv[2] = __builtin_fmaf(q[1].y, g[2], q[1].x);
    wv[3] = __builtin_fmaf(q[1].w, g[3], q[1].z);
    wv[4] = __builtin_fmaf(q[2].y, g[4], q[2].x);
    wv[5] = __builtin_fmaf(q[2].w, g[5], q[2].z);
    wv[6] = __builtin_fmaf(q[3].y, g[6], q[3].x);
    wv[7] = __builtin_fmaf(q[3].w, g[7], q[3].z);

    i32x4 bp;
    #pragma unroll
    for (int h = 0; h < 4; ++h)
      bp[h] = (int)pack_bf16_rne(wv[2 * h], wv[2 * h + 1]);
    bf16x8 bfrag = __builtin_bit_cast(bf16x8, bp);

    #pragma unroll
    for (int mt = 0; mt < 4; ++mt)
      acc[mt] = __builtin_amdgcn_mfma_f32_16x16x32_bf16(af[mt], bfrag, acc[mt], 0, 0, 0);
  };

  bf16x8 afA[4], afB[4];
  float4 qA[4], qB[4];
  int st = wave;
  if (st < NSTEPS) load_step(st, afA, qA);
  while (st < NSTEPS) {
    int n1 = st + 4;
    if (n1 < NSTEPS) load_step(n1, afB, qB);
    __builtin_amdgcn_sched_barrier(0);       // prefetch stays above compute
    compute_step(st, afA, qA);
    st = n1;
    if (st >= NSTEPS) break;
    int n2 = st + 4;
    if (n2 < NSTEPS) load_step(n2, afA, qA);
    __builtin_amdgcn_sched_barrier(0);
    compute_step(st, afB, qB);
    st = n2;
  }

  // reduce the 4 waves' partials through LDS
  __shared__ float red[4 * 16 * 64];   // 16 KB
  #pragma unroll
  for (int mt = 0; mt < 4; ++mt)
    #pragma unroll
    for (int r = 0; r < 4; ++r)
      red[(wave * 16 + mt * 4 + r) * 64 + lane] = acc[mt][r];
  __syncthreads();

  // epilogue: thread -> (m = tid>>2, n-quad = (tid&3)*4), 4 outputs each
  const int m   = tid >> 2;                    // 0..63
  const int nq  = (tid & 3) * 4;               // 0,4,8,12
  const int row = (m >> 4) * 4 + (m & 3);      // mt*4 + r
  const int col = ((m >> 2) & 3) * 16 + nq;    // quad*16 + nq

  float4 p0 = *reinterpret_cast<const float4*>(&red[(0 * 16 + row) * 64 + col]);
  float4 p1 = *reinterpret_cast<const float4*>(&red[(1 * 16 + row) * 64 + col]);
  float4 p2 = *reinterpret_cast<const float4*>(&red[(2 * 16 + row) * 64 + col]);
  float4 p3 = *reinterpret_cast<const float4*>(&red[(3 * 16 + row) * 64 + col]);
  float v0 = (p0.x + p1.x) + (p2.x + p3.x);
  float v1 = (p0.y + p1.y) + (p2.y + p3.y);
  float v2 = (p0.z + p1.z) + (p2.z + p3.z);
  float v3 = (p0.w + p1.w) + (p2.w + p3.w);

  if (F32OUT) {
    float* Out = (float*)OutV;
    float vv[4] = {v0, v1, v2, v3};
    #pragma unroll
    for (int jj = 0; jj < 4; ++jj) {
      int nn = nq + jj;
      if (nn < OVALID)
        Out[((size_t)s * 64 + m) * OVALID + nn] = vv[jj] + bS[s * OVALID + nn];
    }
  } else {
    const float4 b4 = *reinterpret_cast<const float4*>(
        &bS[s * OVALID + bx * 16 + nq]);
    float o0 = v0 + b4.x, o1 = v1 + b4.y, o2 = v2 + b4.z, o3 = v3 + b4.w;
    if (RELU) {
      o0 = fmaxf(o0, 0.0f); o1 = fmaxf(o1, 0.0f);
      o2 = fmaxf(o2, 0.0f); o3 = fmaxf(o3, 0.0f);
    }
    uint2 stv;
    stv.x = pack_bf16_rne(o0, o1);
    stv.y = pack_bf16_rne(o2, o3);
    *reinterpret_cast<uint2*>(
        (unsigned short*)OutV + ((size_t)s * 64 + m) * OPITCH + bx * 16 + nq) = stv;
  }
}

// ---------------------------------------------------------------------------
// Host-side threefry for jax.random.split(key(1), 8)
static void tf_host(unsigned int k0, unsigned int k1, unsigned int c0, unsigned int c1,
                    unsigned int* o0, unsigned int* o1)
{
  const unsigned int ks2 = k0 ^ k1 ^ 0x1BD11BDAu;
  unsigned int x0 = c0 + k0, x1 = c1 + k1;
  TF_R(13) TF_R(15) TF_R(26) TF_R(6)
  x0 += k1;  x1 += ks2 + 1u;
  TF_R(17) TF_R(29) TF_R(16) TF_R(24)
  x0 += ks2; x1 += k0 + 2u;
  TF_R(13) TF_R(15) TF_R(26) TF_R(6)
  x0 += k0;  x1 += k1 + 3u;
  TF_R(17) TF_R(29) TF_R(16) TF_R(24)
  x0 += k1;  x1 += ks2 + 4u;
  TF_R(13) TF_R(15) TF_R(26) TF_R(6)
  x0 += ks2; x1 += k0 + 5u;
  *o0 = x0; *o1 = x1;
}

extern "C" void kernel_launch(void* const* d_in, const int* in_sizes, int n_in,
                              void* d_out, int out_size, void* d_ws, size_t ws_size,
                              hipStream_t stream)
{
  (void)in_sizes; (void)n_in; (void)out_size; (void)ws_size;

  const float* x    = (const float*)d_in[0];
  const float* muW0 = (const float*)d_in[1];
  const float* mub0 = (const float*)d_in[2];
  const float* muW1 = (const float*)d_in[3];
  const float* mub1 = (const float*)d_in[4];
  const float* muW2 = (const float*)d_in[5];
  const float* mub2 = (const float*)d_in[6];
  const float* muW3 = (const float*)d_in[7];
  const float* mub3 = (const float*)d_in[8];
  const float* vW0  = (const float*)d_in[9];
  const float* vb0  = (const float*)d_in[10];
  const float* vW1  = (const float*)d_in[11];
  const float* vb1  = (const float*)d_in[12];
  const float* vW2  = (const float*)d_in[13];
  const float* vb2  = (const float*)d_in[14];
  const float* vW3  = (const float*)d_in[15];
  const float* vb3  = (const float*)d_in[16];

  // keys: split(key(1), 8) -> ks[0]:W0 ks[1]:b0 ks[2]:W1 ks[3]:b1 ...
  unsigned int key[8][2];
  for (unsigned int i = 0; i < 8; ++i)
    tf_host(0u, 1u, 0u, i, &key[i][0], &key[i][1]);

  // ws layout (~25.0 MB; hB aliases msP0 — msP0 is dead once L0 completes)
  char* ws = (char*)d_ws;
  unsigned short* xp = (unsigned short*)(ws);                 // 64*832*2 = 106,496
  unsigned short* hA = (unsigned short*)(ws + 106496);        // 150*64*512*2 = 9,830,400
  float* b0s  = (float*)(ws + 9936896);                       // 150*512*4 = 307,200
  float* b1s  = (float*)(ws + 10244096);
  float* b2s  = (float*)(ws + 10551296);
  float* b3s  = (float*)(ws + 10858496);                      // 150*10*4 (pad 8,192)
  float2* msP1 = (float2*)(ws + 10866688);                    // 2,097,152
  float2* msP2 = (float2*)(ws + 12963840);                    // 2,097,152
  float2* msP3 = (float2*)(ws + 15060992);                    // 65,536
  float2* msP0 = (float2*)(ws + 15126528);                    // 3,407,872
  unsigned short* hB = (unsigned short*)(ws + 15126528);      // aliases msP0

  xpad_kernel<<<208, 256, 0, stream>>>(x, xp);
  pack_kernel<<<3744, 256, 0, stream>>>(muW0, vW0, muW1, vW1, muW2, vW2, muW3, vW3,
                                        msP0, msP1, msP2, msP3);
  bias_kernel<<<906, 256, 0, stream>>>(mub0, vb0, b0s, mub1, vb1, b1s,
                                       mub2, vb2, b2s, mub3, vb3, b3s,
                                       key[1][0], key[1][1], key[3][0], key[3][1],
                                       key[5][0], key[5][1], key[7][0], key[7][1]);

  // Big layers: 1D swizzled grid 4864 = ceil(150/8)*8 * 32 blocks.
  // L0: x(64,784 pad 832) -> hA ; L1: hA -> hB (kills msP0) ; L2: hB -> hA ;
  // L3: hA -> out (tiny, unswizzled)
  layer_fused<784, 832, 512, 512, 0,     832, true,  false>
      <<<4864, 256, 0, stream>>>(xp, hA, msP0, b0s, key[0][0], key[0][1]);
  layer_fused<512, 512, 512, 512, 32768, 512, true,  false>
      <<<4864, 256, 0, stream>>>(hA, hB, msP1, b1s, key[2][0], key[2][1]);
  layer_fused<512, 512, 512, 512, 32768, 512, true,  false>
      <<<4864, 256, 0, stream>>>(hB, hA, msP2, b2s, key[4][0], key[4][1]);
  layer_fused<512, 512, 10,  16,  32768, 512, false, true>
      <<<dim3(1, 150), 256, 0, stream>>>(hA, d_out, msP3, b3s, key[6][0], key[6][1]);
}

// Round 11
// 454.047 us; speedup vs baseline: 1.3417x; 1.0042x over previous
//
#include <hip/hip_runtime.h>

// ---------------------------------------------------------------------------
// BNN MC forward: 150 weight samples of a 784->512->512->512->10 MLP, batch 64.
// Reproduces jax.random (threefry2x32, partitionable=True) exactly (to well
// within the harness absmax threshold).
// R10 = R7 (best structure: 454 us) with two fixes:
//   1) revert R9's XCD swizzle (falsified: FETCH x6 for -4% perf -> kernel is
//      VALU-bound, not memory-bound; swizzle only broke msP L2 sharing).
//   2) L3 restructured: bias3_out initializes d_out with bias, then
//      layer3_atomic K-splits across blocks (grid 4x150, one k-step per wave,
//      RNG exactly once per (s,n,k) instead of x4, atomicAdd f32 partials).
//      Old L3: 150 blocks (0.6/CU latency-bound) + 4x duplicated RNG.
// Evidence base: R8 split (pure RNG stream at 76% occ still ~3x issue model)
// + R9 (6x HBM traffic ~free) => VALU-pipe-bound; VALUBusy~100% is real.
// ws usage ~25.0 MB (hB aliases msP0).
// ---------------------------------------------------------------------------

typedef short bf16x8 __attribute__((ext_vector_type(8)));
typedef int   i32x4  __attribute__((ext_vector_type(4)));
typedef float f32x4  __attribute__((ext_vector_type(4)));

#define TF_R(r) { x0 += x1; x1 = (x1 << (r)) | (x1 >> (32 - (r))); x1 ^= x0; }

// 8-chain round-major threefry pieces (a[8], b[8] in scope)
#define TF8(r) { _Pragma("unroll") for (int j = 0; j < 8; ++j) { \
    a[j] += b[j]; b[j] = (b[j] << (r)) | (b[j] >> (32 - (r))); b[j] ^= a[j]; } }
#define INJ8(kka, kkb) { _Pragma("unroll") for (int j = 0; j < 8; ++j) { \
    a[j] += (kka); b[j] += (kkb); } }

// Threefry-2x32, counter (0, c1), returns x0^x1 — scalar version (bias kernel)
__device__ __forceinline__ unsigned int tf_xor(unsigned int k0, unsigned int k1,
                                               unsigned int c1)
{
  const unsigned int ks2 = k0 ^ k1 ^ 0x1BD11BDAu;
  unsigned int x0 = k0;          // c0 = 0 (+ ks[0])
  unsigned int x1 = c1 + k1;
  TF_R(13) TF_R(15) TF_R(26) TF_R(6)
  x0 += k1;  x1 += ks2 + 1u;
  TF_R(17) TF_R(29) TF_R(16) TF_R(24)
  x0 += ks2; x1 += k0 + 2u;
  TF_R(13) TF_R(15) TF_R(26) TF_R(6)
  x0 += k0;  x1 += k1 + 3u;
  TF_R(17) TF_R(29) TF_R(16) TF_R(24)
  x0 += k1;  x1 += ks2 + 4u;
  TF_R(13) TF_R(15) TF_R(26) TF_R(6)
  x0 += ks2; x1 += k0 + 5u;
  return x0 ^ x1;
}

// bits -> g where eps = sqrt(2)*g; caller folds sqrt(2) into sigma.
// Branchless trimmed Giles erfinv (error << bf16 rounding, see R6 notes).
__device__ __forceinline__ float bits_to_g(unsigned int r)
{
  float f = __uint_as_float((r >> 9) | 0x3F800000u) - 1.0f;   // [0,1)
  float x = __builtin_fmaf(f, 2.0f, -0.99999994f);
  float L = __log2f(__builtin_fmaf(-x, x, 1.0f));             // log2(1-x^2) <= 0
  float t  = __builtin_fmaf(L, -0.6931472f, -2.5f);
  float pc = -4.39150654e-06f;
  pc = __builtin_fmaf(pc, t, 0.00021858087f);
  pc = __builtin_fmaf(pc, t, -0.00125372503f);
  pc = __builtin_fmaf(pc, t, -0.00417768164f);
  pc = __builtin_fmaf(pc, t, 0.246640727f);
  pc = __builtin_fmaf(pc, t, 1.50140941f);
  float w  = L * -0.6931472f;
  float t2 = sqrtf(w) - 3.0f;
  float pt = 0.00573950773f;
  pt = __builtin_fmaf(pt, t2, -0.0076224613f);
  pt = __builtin_fmaf(pt, t2, 0.00943887047f);
  pt = __builtin_fmaf(pt, t2, 1.00167406f);
  pt = __builtin_fmaf(pt, t2, 2.83297682f);
  float p = (L > -7.2134752f) ? pc : pt;    // w < 5
  return p * x;
}

__device__ __forceinline__ unsigned short f32_to_bf16_rne(float v)
{
  unsigned int u = __float_as_uint(v);
  unsigned int r = (u + 0x7FFFu + ((u >> 16) & 1u)) >> 16;   // RNE
  return (unsigned short)r;
}

// pack two f32 -> bf16x2 with RNE: round both in-register, one v_perm_b32.
__device__ __forceinline__ unsigned int pack_bf16_rne(float a, float b)
{
  unsigned int ua = __float_as_uint(a);
  unsigned int ub = __float_as_uint(b);
  ua += 0x7FFFu + ((ua >> 16) & 1u);
  ub += 0x7FFFu + ((ub >> 16) & 1u);
  return __builtin_amdgcn_perm(ub, ua, 0x07060302u);
}

// ---------------------------------------------------------------------------
// x (64,784) fp32 -> bf16, K padded 784 -> 832 with zeros
__global__ __launch_bounds__(256) void xpad_kernel(const float* __restrict__ x,
                                                   unsigned short* __restrict__ xp)
{
  int i = blockIdx.x * 256 + threadIdx.x;          // grid 208 -> 53248 == 64*832
  if (i >= 64 * 832) return;
  int m = i / 832, k = i - m * 832;
  float v = (k < 784) ? x[m * 784 + k] : 0.0f;
  xp[i] = f32_to_bf16_rne(v);
}

// ---------------------------------------------------------------------------
// Pack (mu, exp(v)*sqrt2) into [k/8][n][8] float2, zero-padded in k and n.
__global__ __launch_bounds__(256) void pack_kernel(
    const float* __restrict__ muW0, const float* __restrict__ vW0,
    const float* __restrict__ muW1, const float* __restrict__ vW1,
    const float* __restrict__ muW2, const float* __restrict__ vW2,
    const float* __restrict__ muW3, const float* __restrict__ vW3,
    float2* __restrict__ msP0, float2* __restrict__ msP1,
    float2* __restrict__ msP2, float2* __restrict__ msP3)
{
  int b = blockIdx.x, tid = threadIdx.x;
  const float* mu; const float* v; float2* o;
  int KV, NV, osh, base;
  if (b < 1664)      { mu = muW0; v = vW0; o = msP0; KV = 784; NV = 512; osh = 9; base = 0;    }
  else if (b < 2688) { mu = muW1; v = vW1; o = msP1; KV = 512; NV = 512; osh = 9; base = 1664; }
  else if (b < 3712) { mu = muW2; v = vW2; o = msP2; KV = 512; NV = 512; osh = 9; base = 2688; }
  else               { mu = muW3; v = vW3; o = msP3; KV = 512; NV = 10;  osh = 4; base = 3712; }
  int e = (b - base) * 256 + tid;
  int k = (e & 7) | ((e >> (3 + osh)) << 3);
  int n = (e >> 3) & ((1 << osh) - 1);
  float2 r = {0.0f, 0.0f};
  if (k < KV && n < NV) {
    r.x = mu[n * KV + k];
    r.y = __expf(v[n * KV + k]) * 1.41421356237f;
  }
  o[e] = r;
}

// ---------------------------------------------------------------------------
// Sample all 4 bias tensors -> fp32 in ws.  b_l[s][o] = mu[o] + exp(v[o])*eps
__global__ __launch_bounds__(256) void bias_kernel(
    const float* __restrict__ mu0, const float* __restrict__ v0, float* __restrict__ o0,
    const float* __restrict__ mu1, const float* __restrict__ v1, float* __restrict__ o1,
    const float* __restrict__ mu2, const float* __restrict__ v2, float* __restrict__ o2,
    const float* __restrict__ mu3, const float* __restrict__ v3, float* __restrict__ o3,
    unsigned int k00, unsigned int k01, unsigned int k10, unsigned int k11,
    unsigned int k20, unsigned int k21, unsigned int k30, unsigned int k31)
{
  int b = blockIdx.x, tid = threadIdx.x;
  int seg = b / 300; if (seg > 3) seg = 3;
  const float* mu; const float* v; float* o; unsigned int ka, kb; int n;
  if      (seg == 0) { mu = mu0; v = v0; o = o0; ka = k00; kb = k01; n = 76800; }
  else if (seg == 1) { mu = mu1; v = v1; o = o1; ka = k10; kb = k11; n = 76800; }
  else if (seg == 2) { mu = mu2; v = v2; o = o2; ka = k20; kb = k21; n = 76800; }
  else               { mu = mu3; v = v3; o = o3; ka = k30; kb = k31; n = 1500;  }
  int e = (b - seg * 300) * 256 + tid;
  if (e >= n) return;
  int oo = (seg == 3) ? (e % 10) : (e & 511);
  float eps = 1.41421356237f * bits_to_g(tf_xor(ka, kb, (unsigned int)e));
  o[e] = __builtin_fmaf(__expf(v[oo]), eps, mu[oo]);
}

// ---------------------------------------------------------------------------
// bias3_out: initialize d_out[s][m][n] = b3s[s][n]  (150*64*10 = 96000 f32)
__global__ __launch_bounds__(256) void bias3_out(float* __restrict__ Out,
                                                 const float* __restrict__ b3s)
{
  int i = blockIdx.x * 256 + threadIdx.x;   // grid 375
  if (i >= 96000) return;
  int s = i / 640;
  int rem = i - s * 640;
  int n = rem % 10;
  Out[i] = b3s[s * 10 + n];
}

// ---------------------------------------------------------------------------
// Fused big layer (R7 structure, grid dim3(32,150)):
//   block = 4 waves, one 16-col n-range x all 64 m x full K; K-split across
//   waves; ping-pong register prefetch pinned with sched_barrier(0);
//   LDS reduce; epilogue bias+relu, bf16 out.
// amdgpu_waves_per_eu(1,4): scheduler targets 4 waves/EU, freeing <=128 VGPR.
// mfma_f32_16x16x32_bf16: A/B frag lane holds row (lane&15), k=(lane>>4)*8+j;
// C/D lane holds col n=(lane&15), rows m=(lane>>4)*4+reg.
template<int KVALID, int KPAD, int ASTRIDE, int AROW>
__global__
__attribute__((amdgpu_flat_work_group_size(256, 256)))
__attribute__((amdgpu_waves_per_eu(1, 4)))
void layer_fused(
    const unsigned short* __restrict__ A,   // bf16 [s][64][AROW] (ASTRIDE=0: shared x)
    unsigned short* __restrict__ Out,       // bf16 [s][64][512]
    const float2* __restrict__ msP,         // [KPAD/8][512][8] (mu, sigma*sqrt2)
    const float* __restrict__ bS,           // [s][512]
    unsigned int k0, unsigned int k1)
{
  constexpr int NSTEPS = KPAD / 32;
  constexpr int OVALID = 512, OPITCH = 512;
  const unsigned int ks2 = k0 ^ k1 ^ 0x1BD11BDAu;
  const int s    = blockIdx.y;
  const int tid  = threadIdx.x;
  const int wave = tid >> 6, lane = tid & 63;
  const int quad = lane >> 4;
  const int n16  = lane & 15;
  const int nlane = blockIdx.x * 16 + n16;

  const unsigned short* As = A + (size_t)s * ASTRIDE;
  const unsigned int idx_base = (unsigned int)s * (unsigned int)(OVALID * KVALID)
                              + (unsigned int)nlane * (unsigned int)KVALID;

  f32x4 acc[4] = {f32x4{0,0,0,0}, f32x4{0,0,0,0}, f32x4{0,0,0,0}, f32x4{0,0,0,0}};

  auto load_step = [&](int st, bf16x8 (&af)[4], float4 (&q)[4]) {
    const int kb = st * 32 + quad * 8;
    #pragma unroll
    for (int mt = 0; mt < 4; ++mt)
      af[mt] = *reinterpret_cast<const bf16x8*>(
          As + (size_t)(mt * 16 + n16) * AROW + kb);
    const float4* mp = reinterpret_cast<const float4*>(
        msP + ((size_t)(kb >> 3) * OPITCH + nlane) * 8);
    #pragma unroll
    for (int h = 0; h < 4; ++h)
      q[h] = mp[h];
  };

  auto compute_step = [&](int st, bf16x8 (&af)[4], float4 (&q)[4]) {
    const int kb = st * 32 + quad * 8;
    unsigned int a[8], b[8];
    const unsigned int cb = idx_base + (unsigned int)kb + k1;
    #pragma unroll
    for (int j = 0; j < 8; ++j) { a[j] = k0; b[j] = cb + (unsigned int)j; }
    TF8(13) TF8(15) TF8(26) TF8(6)  INJ8(k1, ks2 + 1u)
    TF8(17) TF8(29) TF8(16) TF8(24) INJ8(ks2, k0 + 2u)
    TF8(13) TF8(15) TF8(26) TF8(6)  INJ8(k0, k1 + 3u)
    TF8(17) TF8(29) TF8(16) TF8(24) INJ8(k1, ks2 + 4u)
    TF8(13) TF8(15) TF8(26) TF8(6)  INJ8(ks2, k0 + 5u)

    float g[8];
    #pragma unroll
    for (int j = 0; j < 8; ++j)
      g[j] = bits_to_g(a[j] ^ b[j]);

    float wv[8];
    wv[0] = __builtin_fmaf(q[0].y, g[0], q[0].x);
    wv[1] = __builtin_fmaf(q[0].w, g[1], q[0].z);
    wv[2] = __builtin_fmaf(q[1].y, g[2], q[1].x);
    wv[3] = __builtin_fmaf(q[1].w, g[3], q[1].z);
    wv[4] = __builtin_fmaf(q[2].y, g[4], q[2].x);
    wv[5] = __builtin_fmaf(q[2].w, g[5], q[2].z);
    wv[6] = __builtin_fmaf(q[3].y, g[6], q[3].x);
    wv[7] = __builtin_fmaf(q[3].w, g[7], q[3].z);

    i32x4 bp;
    #pragma unroll
    for (int h = 0; h < 4; ++h)
      bp[h] = (int)pack_bf16_rne(wv[2 * h], wv[2 * h + 1]);
    bf16x8 bfrag = __builtin_bit_cast(bf16x8, bp);

    #pragma unroll
    for (int mt = 0; mt < 4; ++mt)
      acc[mt] = __builtin_amdgcn_mfma_f32_16x16x32_bf16(af[mt], bfrag, acc[mt], 0, 0, 0);
  };

  bf16x8 afA[4], afB[4];
  float4 qA[4], qB[4];
  int st = wave;
  if (st < NSTEPS) load_step(st, afA, qA);
  while (st < NSTEPS) {
    int n1 = st + 4;
    if (n1 < NSTEPS) load_step(n1, afB, qB);
    __builtin_amdgcn_sched_barrier(0);       // prefetch stays above compute
    compute_step(st, afA, qA);
    st = n1;
    if (st >= NSTEPS) break;
    int n2 = st + 4;
    if (n2 < NSTEPS) load_step(n2, afA, qA);
    __builtin_amdgcn_sched_barrier(0);
    compute_step(st, afB, qB);
    st = n2;
  }

  // reduce the 4 waves' partials through LDS
  __shared__ float red[4 * 16 * 64];   // 16 KB
  #pragma unroll
  for (int mt = 0; mt < 4; ++mt)
    #pragma unroll
    for (int r = 0; r < 4; ++r)
      red[(wave * 16 + mt * 4 + r) * 64 + lane] = acc[mt][r];
  __syncthreads();

  // epilogue: thread -> (m = tid>>2, n-quad = (tid&3)*4), 4 outputs each
  const int m   = tid >> 2;                    // 0..63
  const int nq  = (tid & 3) * 4;               // 0,4,8,12
  const int row = (m >> 4) * 4 + (m & 3);      // mt*4 + r
  const int col = ((m >> 2) & 3) * 16 + nq;    // quad*16 + nq

  float4 p0 = *reinterpret_cast<const float4*>(&red[(0 * 16 + row) * 64 + col]);
  float4 p1 = *reinterpret_cast<const float4*>(&red[(1 * 16 + row) * 64 + col]);
  float4 p2 = *reinterpret_cast<const float4*>(&red[(2 * 16 + row) * 64 + col]);
  float4 p3 = *reinterpret_cast<const float4*>(&red[(3 * 16 + row) * 64 + col]);
  float v0 = (p0.x + p1.x) + (p2.x + p3.x);
  float v1 = (p0.y + p1.y) + (p2.y + p3.y);
  float v2 = (p0.z + p1.z) + (p2.z + p3.z);
  float v3 = (p0.w + p1.w) + (p2.w + p3.w);

  const float4 b4 = *reinterpret_cast<const float4*>(
      &bS[s * OVALID + blockIdx.x * 16 + nq]);
  float o0 = fmaxf(v0 + b4.x, 0.0f), o1 = fmaxf(v1 + b4.y, 0.0f);
  float o2 = fmaxf(v2 + b4.z, 0.0f), o3 = fmaxf(v3 + b4.w, 0.0f);
  uint2 stv;
  stv.x = pack_bf16_rne(o0, o1);
  stv.y = pack_bf16_rne(o2, o3);
  *reinterpret_cast<uint2*>(
      Out + ((size_t)s * 64 + m) * OPITCH + blockIdx.x * 16 + nq) = stv;
}

// ---------------------------------------------------------------------------
// layer3_atomic: last layer with K-split ACROSS BLOCKS. grid dim3(4,150):
// block bx covers k-steps [bx*4, bx*4+4), one step per wave (RNG exactly once
// per (s,n,k) in the whole grid). 4-wave LDS reduce, then atomicAdd f32
// partials onto d_out (pre-initialized with bias by bias3_out).
__global__ __launch_bounds__(256) void layer3_atomic(
    const unsigned short* __restrict__ A,   // bf16 [s][64][512]
    float* __restrict__ Out,                // f32 [s][64][10], bias pre-added
    const float2* __restrict__ msP,         // [64][16][8] (mu, sigma*sqrt2), n-padded
    unsigned int k0, unsigned int k1)
{
  const unsigned int ks2 = k0 ^ k1 ^ 0x1BD11BDAu;
  const int s    = blockIdx.y;
  const int tid  = threadIdx.x;
  const int wave = tid >> 6, lane = tid & 63;
  const int quad = lane >> 4;
  const int n    = lane & 15;

  const unsigned short* As = A + (size_t)s * (64 * 512);
  const int st = blockIdx.x * 4 + wave;      // 0..15
  const int kb = st * 32 + quad * 8;
  const unsigned int idx_base = (unsigned int)s * 5120u + (unsigned int)n * 512u;

  // mu/sigma (padded n in [10,16) have mu=sigma=0 -> weight 0)
  const float4* mp = reinterpret_cast<const float4*>(
      msP + ((size_t)(kb >> 3) * 16 + n) * 8);
  float4 q0 = mp[0], q1 = mp[1], q2 = mp[2], q3 = mp[3];

  unsigned int a[8], b[8];
  const unsigned int cb = idx_base + (unsigned int)kb + k1;
  #pragma unroll
  for (int j = 0; j < 8; ++j) { a[j] = k0; b[j] = cb + (unsigned int)j; }
  TF8(13) TF8(15) TF8(26) TF8(6)  INJ8(k1, ks2 + 1u)
  TF8(17) TF8(29) TF8(16) TF8(24) INJ8(ks2, k0 + 2u)
  TF8(13) TF8(15) TF8(26) TF8(6)  INJ8(k0, k1 + 3u)
  TF8(17) TF8(29) TF8(16) TF8(24) INJ8(k1, ks2 + 4u)
  TF8(13) TF8(15) TF8(26) TF8(6)  INJ8(ks2, k0 + 5u)

  float g[8];
  #pragma unroll
  for (int j = 0; j < 8; ++j)
    g[j] = bits_to_g(a[j] ^ b[j]);

  float wv[8];
  wv[0] = __builtin_fmaf(q0.y, g[0], q0.x);
  wv[1] = __builtin_fmaf(q0.w, g[1], q0.z);
  wv[2] = __builtin_fmaf(q1.y, g[2], q1.x);
  wv[3] = __builtin_fmaf(q1.w, g[3], q1.z);
  wv[4] = __builtin_fmaf(q2.y, g[4], q2.x);
  wv[5] = __builtin_fmaf(q2.w, g[5], q2.z);
  wv[6] = __builtin_fmaf(q3.y, g[6], q3.x);
  wv[7] = __builtin_fmaf(q3.w, g[7], q3.z);

  i32x4 bp;
  #pragma unroll
  for (int h = 0; h < 4; ++h)
    bp[h] = (int)pack_bf16_rne(wv[2 * h], wv[2 * h + 1]);
  bf16x8 bfrag = __builtin_bit_cast(bf16x8, bp);

  f32x4 acc[4] = {f32x4{0,0,0,0}, f32x4{0,0,0,0}, f32x4{0,0,0,0}, f32x4{0,0,0,0}};
  #pragma unroll
  for (int mt = 0; mt < 4; ++mt) {
    bf16x8 afrag = *reinterpret_cast<const bf16x8*>(
        As + (size_t)(mt * 16 + n) * 512 + kb);
    acc[mt] = __builtin_amdgcn_mfma_f32_16x16x32_bf16(afrag, bfrag, acc[mt], 0, 0, 0);
  }

  __shared__ float red[4 * 16 * 64];   // 16 KB
  #pragma unroll
  for (int mt = 0; mt < 4; ++mt)
    #pragma unroll
    for (int r = 0; r < 4; ++r)
      red[(wave * 16 + mt * 4 + r) * 64 + lane] = acc[mt][r];
  __syncthreads();

  const int m   = tid >> 2;                    // 0..63
  const int nq  = (tid & 3) * 4;               // 0,4,8,12
  const int row = (m >> 4) * 4 + (m & 3);
  const int col = ((m >> 2) & 3) * 16 + nq;

  float4 p0 = *reinterpret_cast<const float4*>(&red[(0 * 16 + row) * 64 + col]);
  float4 p1 = *reinterpret_cast<const float4*>(&red[(1 * 16 + row) * 64 + col]);
  float4 p2 = *reinterpret_cast<const float4*>(&red[(2 * 16 + row) * 64 + col]);
  float4 p3 = *reinterpret_cast<const float4*>(&red[(3 * 16 + row) * 64 + col]);
  float vv[4];
  vv[0] = (p0.x + p1.x) + (p2.x + p3.x);
  vv[1] = (p0.y + p1.y) + (p2.y + p3.y);
  vv[2] = (p0.z + p1.z) + (p2.z + p3.z);
  vv[3] = (p0.w + p1.w) + (p2.w + p3.w);

  #pragma unroll
  for (int jj = 0; jj < 4; ++jj) {
    int nn = nq + jj;
    if (nn < 10)
      atomicAdd(&Out[((size_t)s * 64 + m) * 10 + nn], vv[jj]);
  }
}

// ---------------------------------------------------------------------------
// Host-side threefry for jax.random.split(key(1), 8)
static void tf_host(unsigned int k0, unsigned int k1, unsigned int c0, unsigned int c1,
                    unsigned int* o0, unsigned int* o1)
{
  const unsigned int ks2 = k0 ^ k1 ^ 0x1BD11BDAu;
  unsigned int x0 = c0 + k0, x1 = c1 + k1;
  TF_R(13) TF_R(15) TF_R(26) TF_R(6)
  x0 += k1;  x1 += ks2 + 1u;
  TF_R(17) TF_R(29) TF_R(16) TF_R(24)
  x0 += ks2; x1 += k0 + 2u;
  TF_R(13) TF_R(15) TF_R(26) TF_R(6)
  x0 += k0;  x1 += k1 + 3u;
  TF_R(17) TF_R(29) TF_R(16) TF_R(24)
  x0 += k1;  x1 += ks2 + 4u;
  TF_R(13) TF_R(15) TF_R(26) TF_R(6)
  x0 += ks2; x1 += k0 + 5u;
  *o0 = x0; *o1 = x1;
}

extern "C" void kernel_launch(void* const* d_in, const int* in_sizes, int n_in,
                              void* d_out, int out_size, void* d_ws, size_t ws_size,
                              hipStream_t stream)
{
  (void)in_sizes; (void)n_in; (void)out_size; (void)ws_size;

  const float* x    = (const float*)d_in[0];
  const float* muW0 = (const float*)d_in[1];
  const float* mub0 = (const float*)d_in[2];
  const float* muW1 = (const float*)d_in[3];
  const float* mub1 = (const float*)d_in[4];
  const float* muW2 = (const float*)d_in[5];
  const float* mub2 = (const float*)d_in[6];
  const float* muW3 = (const float*)d_in[7];
  const float* mub3 = (const float*)d_in[8];
  const float* vW0  = (const float*)d_in[9];
  const float* vb0  = (const float*)d_in[10];
  const float* vW1  = (const float*)d_in[11];
  const float* vb1  = (const float*)d_in[12];
  const float* vW2  = (const float*)d_in[13];
  const float* vb2  = (const float*)d_in[14];
  const float* vW3  = (const float*)d_in[15];
  const float* vb3  = (const float*)d_in[16];

  // keys: split(key(1), 8) -> ks[0]:W0 ks[1]:b0 ks[2]:W1 ks[3]:b1 ...
  unsigned int key[8][2];
  for (unsigned int i = 0; i < 8; ++i)
    tf_host(0u, 1u, 0u, i, &key[i][0], &key[i][1]);

  // ws layout (~25.0 MB; hB aliases msP0 — msP0 is dead once L0 completes)
  char* ws = (char*)d_ws;
  unsigned short* xp = (unsigned short*)(ws);                 // 64*832*2 = 106,496
  unsigned short* hA = (unsigned short*)(ws + 106496);        // 150*64*512*2 = 9,830,400
  float* b0s  = (float*)(ws + 9936896);                       // 150*512*4 = 307,200
  float* b1s  = (float*)(ws + 10244096);
  float* b2s  = (float*)(ws + 10551296);
  float* b3s  = (float*)(ws + 10858496);                      // 150*10*4 (pad 8,192)
  float2* msP1 = (float2*)(ws + 10866688);                    // 2,097,152
  float2* msP2 = (float2*)(ws + 12963840);                    // 2,097,152
  float2* msP3 = (float2*)(ws + 15060992);                    // 65,536
  float2* msP0 = (float2*)(ws + 15126528);                    // 3,407,872
  unsigned short* hB = (unsigned short*)(ws + 15126528);      // aliases msP0

  xpad_kernel<<<208, 256, 0, stream>>>(x, xp);
  pack_kernel<<<3744, 256, 0, stream>>>(muW0, vW0, muW1, vW1, muW2, vW2, muW3, vW3,
                                        msP0, msP1, msP2, msP3);
  bias_kernel<<<906, 256, 0, stream>>>(mub0, vb0, b0s, mub1, vb1, b1s,
                                       mub2, vb2, b2s, mub3, vb3, b3s,
                                       key[1][0], key[1][1], key[3][0], key[3][1],
                                       key[5][0], key[5][1], key[7][0], key[7][1]);
  bias3_out<<<375, 256, 0, stream>>>((float*)d_out, b3s);

  // L0: x(64,784 pad 832) -> hA ; L1: hA -> hB (kills msP0) ; L2: hB -> hA ;
  // L3: hA -> out (K-split atomic, RNG x1)
  layer_fused<784, 832, 0,     832><<<dim3(32, 150), 256, 0, stream>>>(
      xp, hA, msP0, b0s, key[0][0], key[0][1]);
  layer_fused<512, 512, 32768, 512><<<dim3(32, 150), 256, 0, stream>>>(
      hA, hB, msP1, b1s, key[2][0], key[2][1]);
  layer_fused<512, 512, 32768, 512><<<dim3(32, 150), 256, 0, stream>>>(
      hB, hA, msP2, b2s, key[4][0], key[4][1]);
  layer3_atomic<<<dim3(4, 150), 256, 0, stream>>>(
      hA, (float*)d_out, msP3, key[6][0], key[6][1]);
}

// Round 12
// 419.395 us; speedup vs baseline: 1.4526x; 1.0826x over previous
//
#include <hip/hip_runtime.h>

// ---------------------------------------------------------------------------
// BNN MC forward: 150 weight samples of a 784->512->512->512->10 MLP, batch 64.
// Reproduces jax.random (threefry2x32, partitionable=True) exactly (to well
// within the harness absmax threshold).
// R11 = R10 + instruction diet on the VALU-bound RNG stream (all structural
// theories falsified by experiment; VALUBusy>100% everywhere):
//   1) branchy erfinv tail (exec-mask skip, ~80% of draws skip ~7 VALU ops;
//      same selected values -> bit-identical output).
//   2) v_cvt_pk_bf16_f32 for weight/activation packing (guarded by
//      __has_builtin; fallback = proven manual RNE trick).
// ws usage ~25.0 MB (hB aliases msP0).
// ---------------------------------------------------------------------------

typedef short bf16x8 __attribute__((ext_vector_type(8)));
typedef int   i32x4  __attribute__((ext_vector_type(4)));
typedef float f32x4  __attribute__((ext_vector_type(4)));

#define TF_R(r) { x0 += x1; x1 = (x1 << (r)) | (x1 >> (32 - (r))); x1 ^= x0; }

// 8-chain round-major threefry pieces (a[8], b[8] in scope)
#define TF8(r) { _Pragma("unroll") for (int j = 0; j < 8; ++j) { \
    a[j] += b[j]; b[j] = (b[j] << (r)) | (b[j] >> (32 - (r))); b[j] ^= a[j]; } }
#define INJ8(kka, kkb) { _Pragma("unroll") for (int j = 0; j < 8; ++j) { \
    a[j] += (kka); b[j] += (kkb); } }

// Threefry-2x32, counter (0, c1), returns x0^x1 — scalar version (bias kernel)
__device__ __forceinline__ unsigned int tf_xor(unsigned int k0, unsigned int k1,
                                               unsigned int c1)
{
  const unsigned int ks2 = k0 ^ k1 ^ 0x1BD11BDAu;
  unsigned int x0 = k0;          // c0 = 0 (+ ks[0])
  unsigned int x1 = c1 + k1;
  TF_R(13) TF_R(15) TF_R(26) TF_R(6)
  x0 += k1;  x1 += ks2 + 1u;
  TF_R(17) TF_R(29) TF_R(16) TF_R(24)
  x0 += ks2; x1 += k0 + 2u;
  TF_R(13) TF_R(15) TF_R(26) TF_R(6)
  x0 += k0;  x1 += k1 + 3u;
  TF_R(17) TF_R(29) TF_R(16) TF_R(24)
  x0 += k1;  x1 += ks2 + 4u;
  TF_R(13) TF_R(15) TF_R(26) TF_R(6)
  x0 += ks2; x1 += k0 + 5u;
  return x0 ^ x1;
}

// bits -> g where eps = sqrt(2)*g; caller folds sqrt(2) into sigma.
// Trimmed Giles erfinv (error << bf16 rounding, see R6 notes). R11: tail
// branch is exec-masked (rare: P(any of 64 lanes in tail) ~ 20% per draw) —
// selected values identical to the branchless version.
__device__ __forceinline__ float bits_to_g(unsigned int r)
{
  float f = __uint_as_float((r >> 9) | 0x3F800000u) - 1.0f;   // [0,1)
  float x = __builtin_fmaf(f, 2.0f, -0.99999994f);
  float L = __log2f(__builtin_fmaf(-x, x, 1.0f));             // log2(1-x^2) <= 0
  float t  = __builtin_fmaf(L, -0.6931472f, -2.5f);
  float p = -4.39150654e-06f;
  p = __builtin_fmaf(p, t, 0.00021858087f);
  p = __builtin_fmaf(p, t, -0.00125372503f);
  p = __builtin_fmaf(p, t, -0.00417768164f);
  p = __builtin_fmaf(p, t, 0.246640727f);
  p = __builtin_fmaf(p, t, 1.50140941f);
  if (__builtin_expect(L <= -7.2134752f, 0)) {   // w >= 5: rare tail (0.34%)
    float w  = L * -0.6931472f;
    float t2 = sqrtf(w) - 3.0f;
    float pt = 0.00573950773f;
    pt = __builtin_fmaf(pt, t2, -0.0076224613f);
    pt = __builtin_fmaf(pt, t2, 0.00943887047f);
    pt = __builtin_fmaf(pt, t2, 1.00167406f);
    pt = __builtin_fmaf(pt, t2, 2.83297682f);
    p = pt;
  }
  return p * x;
}

__device__ __forceinline__ unsigned short f32_to_bf16_rne(float v)
{
  unsigned int u = __float_as_uint(v);
  unsigned int r = (u + 0x7FFFu + ((u >> 16) & 1u)) >> 16;   // RNE
  return (unsigned short)r;
}

// pack two f32 -> bf16x2 with RNE. a -> low 16, b -> high 16.
// gfx950 has v_cvt_pk_bf16_f32 (1 inst); fallback = manual RNE (proven).
__device__ __forceinline__ unsigned int pack_bf16_rne(float a, float b)
{
#if __has_builtin(__builtin_amdgcn_cvt_pk_bf16_f32)
  typedef __bf16 bf16x2_t __attribute__((ext_vector_type(2)));
  bf16x2_t r = __builtin_amdgcn_cvt_pk_bf16_f32(a, b);   // src0 -> lo
  return __builtin_bit_cast(unsigned int, r);
#else
  unsigned int ua = __float_as_uint(a);
  unsigned int ub = __float_as_uint(b);
  ua += 0x7FFFu + ((ua >> 16) & 1u);
  ub += 0x7FFFu + ((ub >> 16) & 1u);
  return __builtin_amdgcn_perm(ub, ua, 0x07060302u);
#endif
}

// ---------------------------------------------------------------------------
// x (64,784) fp32 -> bf16, K padded 784 -> 832 with zeros
__global__ __launch_bounds__(256) void xpad_kernel(const float* __restrict__ x,
                                                   unsigned short* __restrict__ xp)
{
  int i = blockIdx.x * 256 + threadIdx.x;          // grid 208 -> 53248 == 64*832
  if (i >= 64 * 832) return;
  int m = i / 832, k = i - m * 832;
  float v = (k < 784) ? x[m * 784 + k] : 0.0f;
  xp[i] = f32_to_bf16_rne(v);
}

// ---------------------------------------------------------------------------
// Pack (mu, exp(v)*sqrt2) into [k/8][n][8] float2, zero-padded in k and n.
__global__ __launch_bounds__(256) void pack_kernel(
    const float* __restrict__ muW0, const float* __restrict__ vW0,
    const float* __restrict__ muW1, const float* __restrict__ vW1,
    const float* __restrict__ muW2, const float* __restrict__ vW2,
    const float* __restrict__ muW3, const float* __restrict__ vW3,
    float2* __restrict__ msP0, float2* __restrict__ msP1,
    float2* __restrict__ msP2, float2* __restrict__ msP3)
{
  int b = blockIdx.x, tid = threadIdx.x;
  const float* mu; const float* v; float2* o;
  int KV, NV, osh, base;
  if (b < 1664)      { mu = muW0; v = vW0; o = msP0; KV = 784; NV = 512; osh = 9; base = 0;    }
  else if (b < 2688) { mu = muW1; v = vW1; o = msP1; KV = 512; NV = 512; osh = 9; base = 1664; }
  else if (b < 3712) { mu = muW2; v = vW2; o = msP2; KV = 512; NV = 512; osh = 9; base = 2688; }
  else               { mu = muW3; v = vW3; o = msP3; KV = 512; NV = 10;  osh = 4; base = 3712; }
  int e = (b - base) * 256 + tid;
  int k = (e & 7) | ((e >> (3 + osh)) << 3);
  int n = (e >> 3) & ((1 << osh) - 1);
  float2 r = {0.0f, 0.0f};
  if (k < KV && n < NV) {
    r.x = mu[n * KV + k];
    r.y = __expf(v[n * KV + k]) * 1.41421356237f;
  }
  o[e] = r;
}

// ---------------------------------------------------------------------------
// Sample all 4 bias tensors -> fp32 in ws.  b_l[s][o] = mu[o] + exp(v[o])*eps
__global__ __launch_bounds__(256) void bias_kernel(
    const float* __restrict__ mu0, const float* __restrict__ v0, float* __restrict__ o0,
    const float* __restrict__ mu1, const float* __restrict__ v1, float* __restrict__ o1,
    const float* __restrict__ mu2, const float* __restrict__ v2, float* __restrict__ o2,
    const float* __restrict__ mu3, const float* __restrict__ v3, float* __restrict__ o3,
    unsigned int k00, unsigned int k01, unsigned int k10, unsigned int k11,
    unsigned int k20, unsigned int k21, unsigned int k30, unsigned int k31)
{
  int b = blockIdx.x, tid = threadIdx.x;
  int seg = b / 300; if (seg > 3) seg = 3;
  const float* mu; const float* v; float* o; unsigned int ka, kb; int n;
  if      (seg == 0) { mu = mu0; v = v0; o = o0; ka = k00; kb = k01; n = 76800; }
  else if (seg == 1) { mu = mu1; v = v1; o = o1; ka = k10; kb = k11; n = 76800; }
  else if (seg == 2) { mu = mu2; v = v2; o = o2; ka = k20; kb = k21; n = 76800; }
  else               { mu = mu3; v = v3; o = o3; ka = k30; kb = k31; n = 1500;  }
  int e = (b - seg * 300) * 256 + tid;
  if (e >= n) return;
  int oo = (seg == 3) ? (e % 10) : (e & 511);
  float eps = 1.41421356237f * bits_to_g(tf_xor(ka, kb, (unsigned int)e));
  o[e] = __builtin_fmaf(__expf(v[oo]), eps, mu[oo]);
}

// ---------------------------------------------------------------------------
// bias3_out: initialize d_out[s][m][n] = b3s[s][n]  (150*64*10 = 96000 f32)
__global__ __launch_bounds__(256) void bias3_out(float* __restrict__ Out,
                                                 const float* __restrict__ b3s)
{
  int i = blockIdx.x * 256 + threadIdx.x;   // grid 375
  if (i >= 96000) return;
  int s = i / 640;
  int rem = i - s * 640;
  int n = rem % 10;
  Out[i] = b3s[s * 10 + n];
}

// ---------------------------------------------------------------------------
// Fused big layer (R7 structure, grid dim3(32,150)):
//   block = 4 waves, one 16-col n-range x all 64 m x full K; K-split across
//   waves; ping-pong register prefetch pinned with sched_barrier(0);
//   LDS reduce; epilogue bias+relu, bf16 out.
// amdgpu_waves_per_eu(1,4): scheduler targets 4 waves/EU, freeing <=128 VGPR.
// mfma_f32_16x16x32_bf16: A/B frag lane holds row (lane&15), k=(lane>>4)*8+j;
// C/D lane holds col n=(lane&15), rows m=(lane>>4)*4+reg.
template<int KVALID, int KPAD, int ASTRIDE, int AROW>
__global__
__attribute__((amdgpu_flat_work_group_size(256, 256)))
__attribute__((amdgpu_waves_per_eu(1, 4)))
void layer_fused(
    const unsigned short* __restrict__ A,   // bf16 [s][64][AROW] (ASTRIDE=0: shared x)
    unsigned short* __restrict__ Out,       // bf16 [s][64][512]
    const float2* __restrict__ msP,         // [KPAD/8][512][8] (mu, sigma*sqrt2)
    const float* __restrict__ bS,           // [s][512]
    unsigned int k0, unsigned int k1)
{
  constexpr int NSTEPS = KPAD / 32;
  constexpr int OVALID = 512, OPITCH = 512;
  const unsigned int ks2 = k0 ^ k1 ^ 0x1BD11BDAu;
  const int s    = blockIdx.y;
  const int tid  = threadIdx.x;
  const int wave = tid >> 6, lane = tid & 63;
  const int quad = lane >> 4;
  const int n16  = lane & 15;
  const int nlane = blockIdx.x * 16 + n16;

  const unsigned short* As = A + (size_t)s * ASTRIDE;
  const unsigned int idx_base = (unsigned int)s * (unsigned int)(OVALID * KVALID)
                              + (unsigned int)nlane * (unsigned int)KVALID;

  f32x4 acc[4] = {f32x4{0,0,0,0}, f32x4{0,0,0,0}, f32x4{0,0,0,0}, f32x4{0,0,0,0}};

  auto load_step = [&](int st, bf16x8 (&af)[4], float4 (&q)[4]) {
    const int kb = st * 32 + quad * 8;
    #pragma unroll
    for (int mt = 0; mt < 4; ++mt)
      af[mt] = *reinterpret_cast<const bf16x8*>(
          As + (size_t)(mt * 16 + n16) * AROW + kb);
    const float4* mp = reinterpret_cast<const float4*>(
        msP + ((size_t)(kb >> 3) * OPITCH + nlane) * 8);
    #pragma unroll
    for (int h = 0; h < 4; ++h)
      q[h] = mp[h];
  };

  auto compute_step = [&](int st, bf16x8 (&af)[4], float4 (&q)[4]) {
    const int kb = st * 32 + quad * 8;
    unsigned int a[8], b[8];
    const unsigned int cb = idx_base + (unsigned int)kb + k1;
    #pragma unroll
    for (int j = 0; j < 8; ++j) { a[j] = k0; b[j] = cb + (unsigned int)j; }
    TF8(13) TF8(15) TF8(26) TF8(6)  INJ8(k1, ks2 + 1u)
    TF8(17) TF8(29) TF8(16) TF8(24) INJ8(ks2, k0 + 2u)
    TF8(13) TF8(15) TF8(26) TF8(6)  INJ8(k0, k1 + 3u)
    TF8(17) TF8(29) TF8(16) TF8(24) INJ8(k1, ks2 + 4u)
    TF8(13) TF8(15) TF8(26) TF8(6)  INJ8(ks2, k0 + 5u)

    float g[8];
    #pragma unroll
    for (int j = 0; j < 8; ++j)
      g[j] = bits_to_g(a[j] ^ b[j]);

    float wv[8];
    wv[0] = __builtin_fmaf(q[0].y, g[0], q[0].x);
    wv[1] = __builtin_fmaf(q[0].w, g[1], q[0].z);
    wv[2] = __builtin_fmaf(q[1].y, g[2], q[1].x);
    wv[3] = __builtin_fmaf(q[1].w, g[3], q[1].z);
    wv[4] = __builtin_fmaf(q[2].y, g[4], q[2].x);
    wv[5] = __builtin_fmaf(q[2].w, g[5], q[2].z);
    wv[6] = __builtin_fmaf(q[3].y, g[6], q[3].x);
    wv[7] = __builtin_fmaf(q[3].w, g[7], q[3].z);

    i32x4 bp;
    #pragma unroll
    for (int h = 0; h < 4; ++h)
      bp[h] = (int)pack_bf16_rne(wv[2 * h], wv[2 * h + 1]);
    bf16x8 bfrag = __builtin_bit_cast(bf16x8, bp);

    #pragma unroll
    for (int mt = 0; mt < 4; ++mt)
      acc[mt] = __builtin_amdgcn_mfma_f32_16x16x32_bf16(af[mt], bfrag, acc[mt], 0, 0, 0);
  };

  bf16x8 afA[4], afB[4];
  float4 qA[4], qB[4];
  int st = wave;
  if (st < NSTEPS) load_step(st, afA, qA);
  while (st < NSTEPS) {
    int n1 = st + 4;
    if (n1 < NSTEPS) load_step(n1, afB, qB);
    __builtin_amdgcn_sched_barrier(0);       // prefetch stays above compute
    compute_step(st, afA, qA);
    st = n1;
    if (st >= NSTEPS) break;
    int n2 = st + 4;
    if (n2 < NSTEPS) load_step(n2, afA, qA);
    __builtin_amdgcn_sched_barrier(0);
    compute_step(st, afB, qB);
    st = n2;
  }

  // reduce the 4 waves' partials through LDS
  __shared__ float red[4 * 16 * 64];   // 16 KB
  #pragma unroll
  for (int mt = 0; mt < 4; ++mt)
    #pragma unroll
    for (int r = 0; r < 4; ++r)
      red[(wave * 16 + mt * 4 + r) * 64 + lane] = acc[mt][r];
  __syncthreads();

  // epilogue: thread -> (m = tid>>2, n-quad = (tid&3)*4), 4 outputs each
  const int m   = tid >> 2;                    // 0..63
  const int nq  = (tid & 3) * 4;               // 0,4,8,12
  const int row = (m >> 4) * 4 + (m & 3);      // mt*4 + r
  const int col = ((m >> 2) & 3) * 16 + nq;    // quad*16 + nq

  float4 p0 = *reinterpret_cast<const float4*>(&red[(0 * 16 + row) * 64 + col]);
  float4 p1 = *reinterpret_cast<const float4*>(&red[(1 * 16 + row) * 64 + col]);
  float4 p2 = *reinterpret_cast<const float4*>(&red[(2 * 16 + row) * 64 + col]);
  float4 p3 = *reinterpret_cast<const float4*>(&red[(3 * 16 + row) * 64 + col]);
  float v0 = (p0.x + p1.x) + (p2.x + p3.x);
  float v1 = (p0.y + p1.y) + (p2.y + p3.y);
  float v2 = (p0.z + p1.z) + (p2.z + p3.z);
  float v3 = (p0.w + p1.w) + (p2.w + p3.w);

  const float4 b4 = *reinterpret_cast<const float4*>(
      &bS[s * OVALID + blockIdx.x * 16 + nq]);
  float o0 = fmaxf(v0 + b4.x, 0.0f), o1 = fmaxf(v1 + b4.y, 0.0f);
  float o2 = fmaxf(v2 + b4.z, 0.0f), o3 = fmaxf(v3 + b4.w, 0.0f);
  uint2 stv;
  stv.x = pack_bf16_rne(o0, o1);
  stv.y = pack_bf16_rne(o2, o3);
  *reinterpret_cast<uint2*>(
      Out + ((size_t)s * 64 + m) * OPITCH + blockIdx.x * 16 + nq) = stv;
}

// ---------------------------------------------------------------------------
// layer3_atomic: last layer with K-split ACROSS BLOCKS. grid dim3(4,150):
// block bx covers k-steps [bx*4, bx*4+4), one step per wave (RNG exactly once
// per (s,n,k)). 4-wave LDS reduce, then atomicAdd f32 partials onto d_out
// (pre-initialized with bias by bias3_out).
__global__ __launch_bounds__(256) void layer3_atomic(
    const unsigned short* __restrict__ A,   // bf16 [s][64][512]
    float* __restrict__ Out,                // f32 [s][64][10], bias pre-added
    const float2* __restrict__ msP,         // [64][16][8] (mu, sigma*sqrt2), n-padded
    unsigned int k0, unsigned int k1)
{
  const unsigned int ks2 = k0 ^ k1 ^ 0x1BD11BDAu;
  const int s    = blockIdx.y;
  const int tid  = threadIdx.x;
  const int wave = tid >> 6, lane = tid & 63;
  const int quad = lane >> 4;
  const int n    = lane & 15;

  const unsigned short* As = A + (size_t)s * (64 * 512);
  const int st = blockIdx.x * 4 + wave;      // 0..15
  const int kb = st * 32 + quad * 8;
  const unsigned int idx_base = (unsigned int)s * 5120u + (unsigned int)n * 512u;

  // mu/sigma (padded n in [10,16) have mu=sigma=0 -> weight 0)
  const float4* mp = reinterpret_cast<const float4*>(
      msP + ((size_t)(kb >> 3) * 16 + n) * 8);
  float4 q0 = mp[0], q1 = mp[1], q2 = mp[2], q3 = mp[3];

  unsigned int a[8], b[8];
  const unsigned int cb = idx_base + (unsigned int)kb + k1;
  #pragma unroll
  for (int j = 0; j < 8; ++j) { a[j] = k0; b[j] = cb + (unsigned int)j; }
  TF8(13) TF8(15) TF8(26) TF8(6)  INJ8(k1, ks2 + 1u)
  TF8(17) TF8(29) TF8(16) TF8(24) INJ8(ks2, k0 + 2u)
  TF8(13) TF8(15) TF8(26) TF8(6)  INJ8(k0, k1 + 3u)
  TF8(17) TF8(29) TF8(16) TF8(24) INJ8(k1, ks2 + 4u)
  TF8(13) TF8(15) TF8(26) TF8(6)  INJ8(ks2, k0 + 5u)

  float g[8];
  #pragma unroll
  for (int j = 0; j < 8; ++j)
    g[j] = bits_to_g(a[j] ^ b[j]);

  float wv[8];
  wv[0] = __builtin_fmaf(q0.y, g[0], q0.x);
  wv[1] = __builtin_fmaf(q0.w, g[1], q0.z);
  wv[2] = __builtin_fmaf(q1.y, g[2], q1.x);
  wv[3] = __builtin_fmaf(q1.w, g[3], q1.z);
  wv[4] = __builtin_fmaf(q2.y, g[4], q2.x);
  wv[5] = __builtin_fmaf(q2.w, g[5], q2.z);
  wv[6] = __builtin_fmaf(q3.y, g[6], q3.x);
  wv[7] = __builtin_fmaf(q3.w, g[7], q3.z);

  i32x4 bp;
  #pragma unroll
  for (int h = 0; h < 4; ++h)
    bp[h] = (int)pack_bf16_rne(wv[2 * h], wv[2 * h + 1]);
  bf16x8 bfrag = __builtin_bit_cast(bf16x8, bp);

  f32x4 acc[4] = {f32x4{0,0,0,0}, f32x4{0,0,0,0}, f32x4{0,0,0,0}, f32x4{0,0,0,0}};
  #pragma unroll
  for (int mt = 0; mt < 4; ++mt) {
    bf16x8 afrag = *reinterpret_cast<const bf16x8*>(
        As + (size_t)(mt * 16 + n) * 512 + kb);
    acc[mt] = __builtin_amdgcn_mfma_f32_16x16x32_bf16(afrag, bfrag, acc[mt], 0, 0, 0);
  }

  __shared__ float red[4 * 16 * 64];   // 16 KB
  #pragma unroll
  for (int mt = 0; mt < 4; ++mt)
    #pragma unroll
    for (int r = 0; r < 4; ++r)
      red[(wave * 16 + mt * 4 + r) * 64 + lane] = acc[mt][r];
  __syncthreads();

  const int m   = tid >> 2;                    // 0..63
  const int nq  = (tid & 3) * 4;               // 0,4,8,12
  const int row = (m >> 4) * 4 + (m & 3);
  const int col = ((m >> 2) & 3) * 16 + nq;

  float4 p0 = *reinterpret_cast<const float4*>(&red[(0 * 16 + row) * 64 + col]);
  float4 p1 = *reinterpret_cast<const float4*>(&red[(1 * 16 + row) * 64 + col]);
  float4 p2 = *reinterpret_cast<const float4*>(&red[(2 * 16 + row) * 64 + col]);
  float4 p3 = *reinterpret_cast<const float4*>(&red[(3 * 16 + row) * 64 + col]);
  float vv[4];
  vv[0] = (p0.x + p1.x) + (p2.x + p3.x);
  vv[1] = (p0.y + p1.y) + (p2.y + p3.y);
  vv[2] = (p0.z + p1.z) + (p2.z + p3.z);
  vv[3] = (p0.w + p1.w) + (p2.w + p3.w);

  #pragma unroll
  for (int jj = 0; jj < 4; ++jj) {
    int nn = nq + jj;
    if (nn < 10)
      atomicAdd(&Out[((size_t)s * 64 + m) * 10 + nn], vv[jj]);
  }
}

// ---------------------------------------------------------------------------
// Host-side threefry for jax.random.split(key(1), 8)
static void tf_host(unsigned int k0, unsigned int k1, unsigned int c0, unsigned int c1,
                    unsigned int* o0, unsigned int* o1)
{
  const unsigned int ks2 = k0 ^ k1 ^ 0x1BD11BDAu;
  unsigned int x0 = c0 + k0, x1 = c1 + k1;
  TF_R(13) TF_R(15) TF_R(26) TF_R(6)
  x0 += k1;  x1 += ks2 + 1u;
  TF_R(17) TF_R(29) TF_R(16) TF_R(24)
  x0 += ks2; x1 += k0 + 2u;
  TF_R(13) TF_R(15) TF_R(26) TF_R(6)
  x0 += k0;  x1 += k1 + 3u;
  TF_R(17) TF_R(29) TF_R(16) TF_R(24)
  x0 += k1;  x1 += ks2 + 4u;
  TF_R(13) TF_R(15) TF_R(26) TF_R(6)
  x0 += ks2; x1 += k0 + 5u;
  *o0 = x0; *o1 = x1;
}

extern "C" void kernel_launch(void* const* d_in, const int* in_sizes, int n_in,
                              void* d_out, int out_size, void* d_ws, size_t ws_size,
                              hipStream_t stream)
{
  (void)in_sizes; (void)n_in; (void)out_size; (void)ws_size;

  const float* x    = (const float*)d_in[0];
  const float* muW0 = (const float*)d_in[1];
  const float* mub0 = (const float*)d_in[2];
  const float* muW1 = (const float*)d_in[3];
  const float* mub1 = (const float*)d_in[4];
  const float* muW2 = (const float*)d_in[5];
  const float* mub2 = (const float*)d_in[6];
  const float* muW3 = (const float*)d_in[7];
  const float* mub3 = (const float*)d_in[8];
  const float* vW0  = (const float*)d_in[9];
  const float* vb0  = (const float*)d_in[10];
  const float* vW1  = (const float*)d_in[11];
  const float* vb1  = (const float*)d_in[12];
  const float* vW2  = (const float*)d_in[13];
  const float* vb2  = (const float*)d_in[14];
  const float* vW3  = (const float*)d_in[15];
  const float* vb3  = (const float*)d_in[16];

  // keys: split(key(1), 8) -> ks[0]:W0 ks[1]:b0 ks[2]:W1 ks[3]:b1 ...
  unsigned int key[8][2];
  for (unsigned int i = 0; i < 8; ++i)
    tf_host(0u, 1u, 0u, i, &key[i][0], &key[i][1]);

  // ws layout (~25.0 MB; hB aliases msP0 — msP0 is dead once L0 completes)
  char* ws = (char*)d_ws;
  unsigned short* xp = (unsigned short*)(ws);                 // 64*832*2 = 106,496
  unsigned short* hA = (unsigned short*)(ws + 106496);        // 150*64*512*2 = 9,830,400
  float* b0s  = (float*)(ws + 9936896);                       // 150*512*4 = 307,200
  float* b1s  = (float*)(ws + 10244096);
  float* b2s  = (float*)(ws + 10551296);
  float* b3s  = (float*)(ws + 10858496);                      // 150*10*4 (pad 8,192)
  float2* msP1 = (float2*)(ws + 10866688);                    // 2,097,152
  float2* msP2 = (float2*)(ws + 12963840);                    // 2,097,152
  float2* msP3 = (float2*)(ws + 15060992);                    // 65,536
  float2* msP0 = (float2*)(ws + 15126528);                    // 3,407,872
  unsigned short* hB = (unsigned short*)(ws + 15126528);      // aliases msP0

  xpad_kernel<<<208, 256, 0, stream>>>(x, xp);
  pack_kernel<<<3744, 256, 0, stream>>>(muW0, vW0, muW1, vW1, muW2, vW2, muW3, vW3,
                                        msP0, msP1, msP2, msP3);
  bias_kernel<<<906, 256, 0, stream>>>(mub0, vb0, b0s, mub1, vb1, b1s,
                                       mub2, vb2, b2s, mub3, vb3, b3s,
                                       key[1][0], key[1][1], key[3][0], key[3][1],
                                       key[5][0], key[5][1], key[7][0], key[7][1]);
  bias3_out<<<375, 256, 0, stream>>>((float*)d_out, b3s);

  // L0: x(64,784 pad 832) -> hA ; L1: hA -> hB (kills msP0) ; L2: hB -> hA ;
  // L3: hA -> out (K-split atomic, RNG x1)
  layer_fused<784, 832, 0,     832><<<dim3(32, 150), 256, 0, stream>>>(
      xp, hA, msP0, b0s, key[0][0], key[0][1]);
  layer_fused<512, 512, 32768, 512><<<dim3(32, 150), 256, 0, stream>>>(
      hA, hB, msP1, b1s, key[2][0], key[2][1]);
  layer_fused<512, 512, 32768, 512><<<dim3(32, 150), 256, 0, stream>>>(
      hB, hA, msP2, b2s, key[4][0], key[4][1]);
  layer3_atomic<<<dim3(4, 150), 256, 0, stream>>>(
      hA, (float*)d_out, msP3, key[6][0], key[6][1]);
}